// Round 8
// baseline (5987.765 us; speedup 1.0000x reference)
//
#include <hip/hip_runtime.h>
#include <cstddef>
#include <cmath>

#define N_TOK 4096
#define D_INF 1024
#define OB_Q 384  // OpenBLAS SGEMM_DEFAULT_Q for Haswell/ZEN (pypi-wheel on EPYC)

typedef unsigned long long u64;

// ---------------- block reduction helpers (256 threads = 4 waves) -------------
__device__ __forceinline__ float blockSum(float x, float* red) {
#pragma unroll
  for (int o = 32; o; o >>= 1) x += __shfl_xor(x, o);
  __syncthreads();
  if ((threadIdx.x & 63) == 0) red[threadIdx.x >> 6] = x;
  __syncthreads();
  return (red[0] + red[1]) + (red[2] + red[3]);
}

// ---------------- numpy float32 exp, bitwise emulation ------------------------
// numpy simd_exp_FLOAT (loops_exponent_log.dispatch): Cephes constants, FMA
// Cody-Waite reduction, Horner, quadrant = rint(x*log2e), exact 2^q scale.
__device__ __forceinline__ float np_expf(float x) {
  const float log2e = 1.44269504088896341f;  // 0x3FB8AA3B
  float q = __builtin_rintf(x * log2e);
  float r = __builtin_fmaf(q, -0.693359375f, x);        // Cody-Waite hi
  r = __builtin_fmaf(q, 2.12194440e-4f, r);             // Cody-Waite lo (-C2)
  float poly = 1.9875691500e-4f;
  poly = __builtin_fmaf(poly, r, 1.3981999507e-3f);
  poly = __builtin_fmaf(poly, r, 8.3334519073e-3f);
  poly = __builtin_fmaf(poly, r, 4.1665795894e-2f);
  poly = __builtin_fmaf(poly, r, 1.6666665459e-1f);
  poly = __builtin_fmaf(poly, r, 5.0000001201e-1f);
  float zz = r * r;                                     // rounded separately
  poly = __builtin_fmaf(poly, zz, r);
  poly = poly + 1.0f;
  return __builtin_ldexpf(poly, (int)q);                // exact 2^q scale
}

// ---------------- numpy pairwise_sum over 4096 floats in LDS ------------------
// 128-element leaves, 8 accumulators, ((r0+r1)+(r2+r3))+((r4+r5)+(r6+r7));
// balanced binary combine of the 32 leaves (butterfly = same association).
__device__ float npPairwiseSum4096(const float* __restrict__ buf, float* share) {
  int t = threadIdx.x;
  __syncthreads();  // buf fully written
  if (t < 32) {
    const float* a = buf + (t << 7);
    float r0 = a[0], r1 = a[1], r2 = a[2], r3 = a[3];
    float r4 = a[4], r5 = a[5], r6 = a[6], r7 = a[7];
    for (int i = 8; i < 128; i += 8) {
      r0 += a[i];     r1 += a[i + 1]; r2 += a[i + 2]; r3 += a[i + 3];
      r4 += a[i + 4]; r5 += a[i + 5]; r6 += a[i + 6]; r7 += a[i + 7];
    }
    float leaf = ((r0 + r1) + (r2 + r3)) + ((r4 + r5) + (r6 + r7));
    leaf += __shfl_xor(leaf, 1);
    leaf += __shfl_xor(leaf, 2);
    leaf += __shfl_xor(leaf, 4);
    leaf += __shfl_xor(leaf, 8);
    leaf += __shfl_xor(leaf, 16);
    if (t == 0) share[0] = leaf;
  }
  __syncthreads();
  return share[0];
}

// ---------------- rowsum of S (+1 for identity), store reciprocal -------------
__global__ __launch_bounds__(256) void rowsum_kernel(const float* __restrict__ S,
                                                     float* __restrict__ rs) {
  __shared__ float red[4];
  const float* s = S + (size_t)blockIdx.x * N_TOK;
  float acc = 0.f;
  for (int j = threadIdx.x; j < N_TOK; j += 256) acc += s[j];
  acc = blockSum(acc, red);
  if (threadIdx.x == 0) rs[blockIdx.x] = 1.0f / fmaxf(acc + 1.0f, 1e-12f);
}

// ---------------- Wcat = [W1 | W3]  (1024 x 128) ------------------------------
__global__ void wcat_kernel(const float* __restrict__ W1,
                            const float* __restrict__ W3, float* __restrict__ Wc) {
  int r = blockIdx.x;
  int c = threadIdx.x;
  Wc[r * 128 + c] = (c < 64) ? W1[r * 64 + c] : W3[r * 64 + (c - 64)];
}

// ---------------- QW = Q @ W2 (Q = QK[:,0:64], ld 128) ------------------------
// K=64: single kc chunk -> plain k-sequential explicit-FMA chain.
__global__ __launch_bounds__(256) void qw_kernel(const float* __restrict__ QK,
                                                 const float* __restrict__ W2,
                                                 float* __restrict__ QW) {
  __shared__ float w[64][65];
  int t = threadIdx.x;
#pragma unroll
  for (int v = 0; v < 16; ++v) {
    int idx = t + v * 256;
    w[idx >> 6][idx & 63] = W2[idx];
  }
  __syncthreads();
  int row = blockIdx.x * 4 + (t >> 6);
  int c = t & 63;
  const float* q = QK + (size_t)row * 128;
  float acc = 0.f;
#pragma unroll
  for (int k = 0; k < 64; ++k) acc = __builtin_fmaf(q[k], w[k][c], acc);
  QW[(size_t)row * 64 + c] = acc;
}

// ---------------- OpenBLAS kc-chunk step (level3.c balanced tail) -------------
// min_l = rem; if rem >= 2Q -> Q; else if rem > Q -> roundup16(rem/2); else rem.
__device__ __forceinline__ int ob_step(int rem) {
  if (rem >= 2 * OB_Q) return OB_Q;
  if (rem > OB_Q) return ((rem / 2) + 15) & ~15;  // round up half to UNROLL=16
  return rem;
}

// ---------------- fp32 tiled GEMM: C = A@B (+C if BETA) -----------------------
// Emulates OpenBLAS sgemm accumulation bitwise: per C element, K split into
// kc chunks per the level3 driver rule (Q=384, balanced tail, round-16);
// within a chunk strictly k-ascending FMA from zero; chunk partials combined
// by plain adds in order ((c0+c1)+c2)...
template <int BETA>
__global__ __launch_bounds__(256) void gemm_tile(const float* __restrict__ A,
                                                 const float* __restrict__ B,
                                                 float* __restrict__ C,
                                                 int M, int N, int K) {
  __shared__ float As[16][68];  // [k][m]
  __shared__ float Bs[16][68];  // [k][n]
  int t = threadIdx.x;
  int tx = t & 15, ty = t >> 4;
  int row0 = blockIdx.y * 64, col0 = blockIdx.x * 64;
  float tot[4][4] = {};
  float acc[4][4] = {};
  int next_b = ob_step(K);  // first chunk boundary
  for (int k0 = 0; k0 < K; k0 += 16) {
    if (k0 == next_b) {  // kc boundary: fold chunk into running total
#pragma unroll
      for (int i = 0; i < 4; ++i)
#pragma unroll
        for (int j = 0; j < 4; ++j) { tot[i][j] += acc[i][j]; acc[i][j] = 0.f; }
      next_b = k0 + ob_step(K - k0);
    }
#pragma unroll
    for (int v = 0; v < 4; ++v) {
      int idx = t + v * 256;
      int r = idx >> 4, c = idx & 15;
      As[c][r] = A[(size_t)(row0 + r) * K + k0 + c];
    }
#pragma unroll
    for (int v = 0; v < 4; ++v) {
      int idx = t + v * 256;
      int r = idx >> 6, c = idx & 63;
      Bs[r][c] = B[(size_t)(k0 + r) * N + col0 + c];
    }
    __syncthreads();
#pragma unroll
    for (int kk = 0; kk < 16; ++kk) {
      float4 a = *(const float4*)&As[kk][ty * 4];
      float4 b = *(const float4*)&Bs[kk][tx * 4];
      float av[4] = {a.x, a.y, a.z, a.w};
      float bv[4] = {b.x, b.y, b.z, b.w};
#pragma unroll
      for (int i = 0; i < 4; ++i)
#pragma unroll
        for (int j = 0; j < 4; ++j)
          acc[i][j] = __builtin_fmaf(av[i], bv[j], acc[i][j]);
    }
    __syncthreads();
  }
#pragma unroll
  for (int i = 0; i < 4; ++i)
#pragma unroll
    for (int j = 0; j < 4; ++j) tot[i][j] += acc[i][j];
#pragma unroll
  for (int i = 0; i < 4; ++i) {
    float* cp = &C[(size_t)(row0 + ty * 4 + i) * N + col0 + tx * 4];
    float4 o;
    if (BETA) {
      float4 old = *(const float4*)cp;
      o.x = old.x + tot[i][0]; o.y = old.y + tot[i][1];
      o.z = old.z + tot[i][2]; o.w = old.w + tot[i][3];
    } else {
      o.x = tot[i][0]; o.y = tot[i][1]; o.z = tot[i][2]; o.w = tot[i][3];
    }
    *(float4*)cp = o;
  }
}

// ---------------- logits = QW @ K^T  (K = QK[:,64:128], ld 128), K=64 ---------
__global__ __launch_bounds__(256) void logits_abt(const float* __restrict__ QW,
                                                  const float* __restrict__ QK,
                                                  float* __restrict__ L) {
  __shared__ float Aq[64][68];  // [c][m]
  __shared__ float Bk[64][68];  // [c][n]
  int t = threadIdx.x;
  int tx = t & 15, ty = t >> 4;
  int row0 = blockIdx.y * 64, col0 = blockIdx.x * 64;
#pragma unroll
  for (int v = 0; v < 16; ++v) {
    int idx = t + v * 256;
    int c = idx & 63, r = idx >> 6;
    Aq[c][r] = QW[(size_t)(row0 + r) * 64 + c];
    Bk[c][r] = QK[(size_t)(col0 + r) * 128 + 64 + c];
  }
  __syncthreads();
  float acc[4][4] = {};
#pragma unroll
  for (int c0 = 0; c0 < 64; ++c0) {
    float4 a = *(const float4*)&Aq[c0][ty * 4];
    float4 b = *(const float4*)&Bk[c0][tx * 4];
    float av[4] = {a.x, a.y, a.z, a.w};
    float bv[4] = {b.x, b.y, b.z, b.w};
#pragma unroll
    for (int i = 0; i < 4; ++i)
#pragma unroll
      for (int j = 0; j < 4; ++j)
        acc[i][j] = __builtin_fmaf(av[i], bv[j], acc[i][j]);
  }
#pragma unroll
  for (int i = 0; i < 4; ++i) {
    float4 o = {acc[i][0], acc[i][1], acc[i][2], acc[i][3]};
    *(float4*)&L[(size_t)(row0 + ty * 4 + i) * N_TOK + col0 + tx * 4] = o;
  }
}

// ---------------- exact top-p, bitwise-numpy fp32 semantics -------------------
// Per row: descending sort (index tiebreak); e = np_expf(v - max);
// tot = np-pairwise-sum(e, sorted order); probs = e/tot (fp32 div);
// sequential fp32 cumsum, k = count(csum < 0.9f) + 1; keep first k ranks;
// A = e_scattered / np-pairwise-sum(e_scattered, COLUMN order, zeros incl).
__global__ __launch_bounds__(256) void topp_exact(float* __restrict__ L) {
  __shared__ u64 key[N_TOK];     // 32 KB
  __shared__ float p[N_TOK];     // 16 KB
  __shared__ float sbuf[N_TOK];  // 16 KB
  __shared__ float fshare;
  __shared__ int kshare;
  __shared__ float mxs;

  float* l = L + (size_t)blockIdx.x * N_TOK;
  int t = threadIdx.x;

  // load + monotone-descending key transform (tie -> lower index first)
  for (int i = t; i < N_TOK; i += 256) {
    float v = l[i];
    unsigned u = __float_as_uint(v);
    unsigned m = (u & 0x80000000u) ? ~u : (u | 0x80000000u);  // ascending map
    key[i] = ((u64)(~m) << 32) | (unsigned)i;                 // asc key = desc v
  }
  __syncthreads();

  // bitonic sort ascending on key (=> values descending, idx asc on ties)
  for (int k = 2; k <= N_TOK; k <<= 1) {
    for (int j = k >> 1; j > 0; j >>= 1) {
      for (int i = t; i < N_TOK; i += 256) {
        int ixj = i ^ j;
        if (ixj > i) {
          u64 a = key[i], b = key[ixj];
          bool asc = ((i & k) == 0);
          if ((a > b) == asc) { key[i] = b; key[ixj] = a; }
        }
      }
      __syncthreads();
    }
  }

  // max value (rank 0)
  if (t == 0) {
    unsigned dk = (unsigned)(key[0] >> 32);
    unsigned m = ~dk;
    unsigned u = (m & 0x80000000u) ? (m ^ 0x80000000u) : ~m;
    mxs = __uint_as_float(u);
  }
  __syncthreads();
  float mx = mxs;

  // e by rank into p
  for (int i = t; i < N_TOK; i += 256) {
    unsigned dk = (unsigned)(key[i] >> 32);
    unsigned m = ~dk;
    unsigned u = (m & 0x80000000u) ? (m ^ 0x80000000u) : ~m;
    float v = __uint_as_float(u);
    p[i] = np_expf(v - mx);
  }
  float tot = npPairwiseSum4096(p, &fshare);  // syncs internally

  // probs = e / tot (fp32 division)
  for (int i = t; i < N_TOK; i += 256) p[i] = p[i] / tot;
  // zero scatter buffer in parallel
  for (int i = t; i < N_TOK; i += 256) sbuf[i] = 0.f;
  __syncthreads();

  // strictly sequential fp32 cumsum; count csum < 0.9f
  if (t == 0) {
    float c = 0.f;
    int cnt = 0;
    for (int j = 0; j < N_TOK; j += 4) {
      float4 q = *(const float4*)&p[j];
      c += q.x; cnt += (c < 0.9f) ? 1 : 0;
      c += q.y; cnt += (c < 0.9f) ? 1 : 0;
      c += q.z; cnt += (c < 0.9f) ? 1 : 0;
      c += q.w; cnt += (c < 0.9f) ? 1 : 0;
    }
    kshare = cnt + 1;
  }
  __syncthreads();
  int kcut = kshare;

  // scatter raw e for kept ranks into column positions
  for (int i = t; i < kcut; i += 256) {
    u64 kk = key[i];
    unsigned dk = (unsigned)(kk >> 32);
    unsigned m = ~dk;
    unsigned u = (m & 0x80000000u) ? (m ^ 0x80000000u) : ~m;
    float v = __uint_as_float(u);
    unsigned col = (unsigned)(kk & 0xFFFFFFFFu);
    sbuf[col] = np_expf(v - mx);
  }
  float denom = npPairwiseSum4096(sbuf, &fshare);  // syncs internally

  // A row = sbuf / denom (fp32 division; zeros stay +0)
  for (int i = t; i < N_TOK; i += 256) l[i] = sbuf[i] / denom;
}

// ---------------- Xf = (T + Xf) * rs[row], vectorized float4 ------------------
__global__ __launch_bounds__(256) void xf_update(float* __restrict__ Xf,
                                                 const float* __restrict__ T,
                                                 const float* __restrict__ rs) {
  int idx = blockIdx.x * 256 + threadIdx.x;  // float4 index; total 1M
  int row = idx >> 8;
  float r = rs[row];
  float4 a = ((const float4*)T)[idx];
  float4 b = ((const float4*)Xf)[idx];
  float4 o;
  o.x = (a.x + b.x) * r; o.y = (a.y + b.y) * r;
  o.z = (a.z + b.z) * r; o.w = (a.w + b.w) * r;
  ((float4*)Xf)[idx] = o;
}

// ---------------- out = LayerNorm(X + Z) * gamma + beta  (Z lives in out) -----
__global__ __launch_bounds__(256) void ln_kernel(const float* __restrict__ X,
                                                 float* __restrict__ out,
                                                 const float* __restrict__ gamma,
                                                 const float* __restrict__ beta) {
  __shared__ float red[4];
  size_t base = (size_t)blockIdx.x * D_INF;
  int t = threadIdx.x;
  float y[4];
  float s = 0.f, ss = 0.f;
#pragma unroll
  for (int i = 0; i < 4; ++i) {
    int c = i * 256 + t;
    y[i] = X[base + c] + out[base + c];
    s += y[i];
    ss += y[i] * y[i];
  }
  s = blockSum(s, red);
  ss = blockSum(ss, red);
  float mean = s * (1.f / 1024.f);
  float var = ss * (1.f / 1024.f) - mean * mean;
  float rstd = rsqrtf(var + 1e-5f);
#pragma unroll
  for (int i = 0; i < 4; ++i) {
    int c = i * 256 + t;
    out[base + c] = (y[i] - mean) * rstd * gamma[c] + beta[c];
  }
}

// -----------------------------------------------------------------------------
extern "C" void kernel_launch(void* const* d_in, const int* in_sizes, int n_in,
                              void* d_out, int out_size, void* d_ws, size_t ws_size,
                              hipStream_t stream) {
  const float* X    = (const float*)d_in[0];
  const float* S    = (const float*)d_in[1];
  const float* W1   = (const float*)d_in[2];
  const float* W2   = (const float*)d_in[3];
  const float* W3   = (const float*)d_in[4];
  const float* U1_0 = (const float*)d_in[5];
  const float* U1_1 = (const float*)d_in[6];
  const float* U2_0 = (const float*)d_in[7];
  const float* U2_1 = (const float*)d_in[8];
  const float* gamma = (const float*)d_in[9];
  const float* beta  = (const float*)d_in[10];
  float* Z = (float*)d_out;  // Z accumulates in d_out; LN finalizes in place

  const size_t ND = (size_t)N_TOK * D_INF;   // 4M
  const size_t NN = (size_t)N_TOK * N_TOK;   // 16M
  float* Xf  = (float*)d_ws;
  float* Xa0 = Xf  + ND;
  float* Xa1 = Xa0 + ND;
  float* T   = Xa1 + ND;
  float* L   = T   + ND;                      // 16M
  float* QKb = L   + NN;                      // 4096x128
  float* QWb = QKb + (size_t)N_TOK * 128;     // 4096x64
  float* Wc  = QWb + (size_t)N_TOK * 64;      // 1024x128
  float* rs  = Wc  + (size_t)D_INF * 128;     // 4096

  hipMemcpyAsync(Xf, X, ND * sizeof(float), hipMemcpyDeviceToDevice, stream);
  rowsum_kernel<<<N_TOK, 256, 0, stream>>>(S, rs);
  wcat_kernel<<<D_INF, 128, 0, stream>>>(W1, W3, Wc);

  // ===== step 0 (Xa = X) =====
  gemm_tile<0><<<dim3(2, 64), 256, 0, stream>>>(X, Wc, QKb, N_TOK, 128, D_INF);
  qw_kernel<<<N_TOK / 4, 256, 0, stream>>>(QKb, W2, QWb);
  logits_abt<<<dim3(64, 64), 256, 0, stream>>>(QWb, QKb, L);
  topp_exact<<<N_TOK, 256, 0, stream>>>(L);                       // A1 in L
  gemm_tile<0><<<dim3(16, 64), 256, 0, stream>>>(S, Xf, T, N_TOK, D_INF, N_TOK);
  xf_update<<<4096, 256, 0, stream>>>(Xf, T, rs);
  gemm_tile<0><<<dim3(16, 64), 256, 0, stream>>>(L, X, Xa0, N_TOK, D_INF, N_TOK);
  gemm_tile<0><<<dim3(16, 64), 256, 0, stream>>>(Xf, U1_0, Z, N_TOK, D_INF, D_INF);
  gemm_tile<1><<<dim3(16, 64), 256, 0, stream>>>(Xa0, U2_0, Z, N_TOK, D_INF, D_INF);

  // ===== step 1 (Xa = Xa0) =====
  gemm_tile<0><<<dim3(2, 64), 256, 0, stream>>>(Xa0, Wc, QKb, N_TOK, 128, D_INF);
  qw_kernel<<<N_TOK / 4, 256, 0, stream>>>(QKb, W2, QWb);
  logits_abt<<<dim3(64, 64), 256, 0, stream>>>(QWb, QKb, L);
  topp_exact<<<N_TOK, 256, 0, stream>>>(L);                       // A2 in L
  gemm_tile<0><<<dim3(16, 64), 256, 0, stream>>>(S, Xf, T, N_TOK, D_INF, N_TOK);
  xf_update<<<4096, 256, 0, stream>>>(Xf, T, rs);
  gemm_tile<0><<<dim3(16, 64), 256, 0, stream>>>(L, Xa0, Xa1, N_TOK, D_INF, N_TOK);
  gemm_tile<1><<<dim3(16, 64), 256, 0, stream>>>(Xf, U1_1, Z, N_TOK, D_INF, D_INF);
  gemm_tile<1><<<dim3(16, 64), 256, 0, stream>>>(Xa1, U2_1, Z, N_TOK, D_INF, D_INF);

  ln_kernel<<<N_TOK, 256, 0, stream>>>(X, Z, gamma, beta);
}

// Round 9
// 4262.976 us; speedup vs baseline: 1.4046x; 1.4046x over previous
//
#include <hip/hip_runtime.h>
#include <cstddef>
#include <cmath>

#define N_TOK 4096
#define D_INF 1024
#define OB_Q 384  // OpenBLAS SGEMM_DEFAULT_Q for Haswell/ZEN (pypi-wheel on EPYC)

typedef unsigned long long u64;

// ---------------- block reduction helpers -------------------------------------
__device__ __forceinline__ float blockSum(float x, float* red) {
#pragma unroll
  for (int o = 32; o; o >>= 1) x += __shfl_xor(x, o);
  __syncthreads();
  if ((threadIdx.x & 63) == 0) red[threadIdx.x >> 6] = x;
  __syncthreads();
  return (red[0] + red[1]) + (red[2] + red[3]);
}

// int reduce for 512-thread block (8 waves)
__device__ __forceinline__ int blockSumI512(int x, int* red) {
#pragma unroll
  for (int o = 32; o; o >>= 1) x += __shfl_xor(x, o);
  __syncthreads();
  if ((threadIdx.x & 63) == 0) red[threadIdx.x >> 6] = x;
  __syncthreads();
  int s = 0;
#pragma unroll
  for (int w = 0; w < 8; ++w) s += red[w];
  return s;
}

// ---------------- numpy float32 exp, bitwise emulation ------------------------
__device__ __forceinline__ float np_expf(float x) {
  const float log2e = 1.44269504088896341f;  // 0x3FB8AA3B
  float q = __builtin_rintf(x * log2e);
  float r = __builtin_fmaf(q, -0.693359375f, x);        // Cody-Waite hi
  r = __builtin_fmaf(q, 2.12194440e-4f, r);             // Cody-Waite lo (-C2)
  float poly = 1.9875691500e-4f;
  poly = __builtin_fmaf(poly, r, 1.3981999507e-3f);
  poly = __builtin_fmaf(poly, r, 8.3334519073e-3f);
  poly = __builtin_fmaf(poly, r, 4.1665795894e-2f);
  poly = __builtin_fmaf(poly, r, 1.6666665459e-1f);
  poly = __builtin_fmaf(poly, r, 5.0000001201e-1f);
  float zz = r * r;                                     // rounded separately
  poly = __builtin_fmaf(poly, zz, r);
  poly = poly + 1.0f;
  return __builtin_ldexpf(poly, (int)q);                // exact 2^q scale
}

// ---------------- numpy pairwise_sum over 4096 floats in LDS ------------------
// 128-element leaves, 8 accumulators, ((r0+r1)+(r2+r3))+((r4+r5)+(r6+r7));
// balanced binary combine of the 32 leaves (butterfly = same association).
__device__ float npPairwiseSum4096(const float* __restrict__ buf, float* share) {
  int t = threadIdx.x;
  __syncthreads();  // buf fully written
  if (t < 32) {
    const float* a = buf + (t << 7);
    float r0 = a[0], r1 = a[1], r2 = a[2], r3 = a[3];
    float r4 = a[4], r5 = a[5], r6 = a[6], r7 = a[7];
    for (int i = 8; i < 128; i += 8) {
      r0 += a[i];     r1 += a[i + 1]; r2 += a[i + 2]; r3 += a[i + 3];
      r4 += a[i + 4]; r5 += a[i + 5]; r6 += a[i + 6]; r7 += a[i + 7];
    }
    float leaf = ((r0 + r1) + (r2 + r3)) + ((r4 + r5) + (r6 + r7));
    leaf += __shfl_xor(leaf, 1);
    leaf += __shfl_xor(leaf, 2);
    leaf += __shfl_xor(leaf, 4);
    leaf += __shfl_xor(leaf, 8);
    leaf += __shfl_xor(leaf, 16);
    if (t == 0) share[0] = leaf;
  }
  __syncthreads();
  return share[0];
}

// key transform: u32 monotone key, ascending key order == descending float order
__device__ __forceinline__ unsigned desc_key(float v) {
  unsigned u = __float_as_uint(v);
  unsigned m = (u & 0x80000000u) ? ~u : (u | 0x80000000u);  // ascending map
  return ~m;
}
__device__ __forceinline__ float desc_key_inv(unsigned k) {
  unsigned m = ~k;
  return __uint_as_float((m & 0x80000000u) ? (m ^ 0x80000000u) : ~m);
}

// ---------------- rowsum of S (+1 for identity), store reciprocal -------------
__global__ __launch_bounds__(256) void rowsum_kernel(const float* __restrict__ S,
                                                     float* __restrict__ rs) {
  __shared__ float red[4];
  const float* s = S + (size_t)blockIdx.x * N_TOK;
  float acc = 0.f;
  for (int j = threadIdx.x; j < N_TOK; j += 256) acc += s[j];
  acc = blockSum(acc, red);
  if (threadIdx.x == 0) rs[blockIdx.x] = 1.0f / fmaxf(acc + 1.0f, 1e-12f);
}

// ---------------- Wcat = [W1 | W3]  (1024 x 128) ------------------------------
__global__ void wcat_kernel(const float* __restrict__ W1,
                            const float* __restrict__ W3, float* __restrict__ Wc) {
  int r = blockIdx.x;
  int c = threadIdx.x;
  Wc[r * 128 + c] = (c < 64) ? W1[r * 64 + c] : W3[r * 64 + (c - 64)];
}

// ---------------- QW = Q @ W2 (Q = QK[:,0:64], ld 128) ------------------------
__global__ __launch_bounds__(256) void qw_kernel(const float* __restrict__ QK,
                                                 const float* __restrict__ W2,
                                                 float* __restrict__ QW) {
  __shared__ float w[64][65];
  int t = threadIdx.x;
#pragma unroll
  for (int v = 0; v < 16; ++v) {
    int idx = t + v * 256;
    w[idx >> 6][idx & 63] = W2[idx];
  }
  __syncthreads();
  int row = blockIdx.x * 4 + (t >> 6);
  int c = t & 63;
  const float* q = QK + (size_t)row * 128;
  float acc = 0.f;
#pragma unroll
  for (int k = 0; k < 64; ++k) acc = __builtin_fmaf(q[k], w[k][c], acc);
  QW[(size_t)row * 64 + c] = acc;
}

// ---------------- OpenBLAS kc-chunk step (level3.c balanced tail) -------------
__device__ __forceinline__ int ob_step(int rem) {
  if (rem >= 2 * OB_Q) return OB_Q;
  if (rem > OB_Q) return ((rem / 2) + 15) & ~15;  // round up half to UNROLL=16
  return rem;
}

// ---------------- fp32 tiled GEMM: C = A@B (+C if BETA) -----------------------
// OpenBLAS-bitwise accumulation (Q=384 balanced-tail kc chunks, per-element
// k-ascending FMA chains, chunk partials joined by plain adds).
template <int BETA>
__global__ __launch_bounds__(256) void gemm_tile(const float* __restrict__ A,
                                                 const float* __restrict__ B,
                                                 float* __restrict__ C,
                                                 int M, int N, int K) {
  __shared__ float As[16][68];  // [k][m]
  __shared__ float Bs[16][68];  // [k][n]
  int t = threadIdx.x;
  int tx = t & 15, ty = t >> 4;
  int row0 = blockIdx.y * 64, col0 = blockIdx.x * 64;
  float tot[4][4] = {};
  float acc[4][4] = {};
  int next_b = ob_step(K);  // first chunk boundary
  for (int k0 = 0; k0 < K; k0 += 16) {
    if (k0 == next_b) {  // kc boundary: fold chunk into running total
#pragma unroll
      for (int i = 0; i < 4; ++i)
#pragma unroll
        for (int j = 0; j < 4; ++j) { tot[i][j] += acc[i][j]; acc[i][j] = 0.f; }
      next_b = k0 + ob_step(K - k0);
    }
#pragma unroll
    for (int v = 0; v < 4; ++v) {
      int idx = t + v * 256;
      int r = idx >> 4, c = idx & 15;
      As[c][r] = A[(size_t)(row0 + r) * K + k0 + c];
    }
#pragma unroll
    for (int v = 0; v < 4; ++v) {
      int idx = t + v * 256;
      int r = idx >> 6, c = idx & 63;
      Bs[r][c] = B[(size_t)(k0 + r) * N + col0 + c];
    }
    __syncthreads();
#pragma unroll
    for (int kk = 0; kk < 16; ++kk) {
      float4 a = *(const float4*)&As[kk][ty * 4];
      float4 b = *(const float4*)&Bs[kk][tx * 4];
      float av[4] = {a.x, a.y, a.z, a.w};
      float bv[4] = {b.x, b.y, b.z, b.w};
#pragma unroll
      for (int i = 0; i < 4; ++i)
#pragma unroll
        for (int j = 0; j < 4; ++j)
          acc[i][j] = __builtin_fmaf(av[i], bv[j], acc[i][j]);
    }
    __syncthreads();
  }
#pragma unroll
  for (int i = 0; i < 4; ++i)
#pragma unroll
    for (int j = 0; j < 4; ++j) tot[i][j] += acc[i][j];
#pragma unroll
  for (int i = 0; i < 4; ++i) {
    float* cp = &C[(size_t)(row0 + ty * 4 + i) * N + col0 + tx * 4];
    float4 o;
    if (BETA) {
      float4 old = *(const float4*)cp;
      o.x = old.x + tot[i][0]; o.y = old.y + tot[i][1];
      o.z = old.z + tot[i][2]; o.w = old.w + tot[i][3];
    } else {
      o.x = tot[i][0]; o.y = tot[i][1]; o.z = tot[i][2]; o.w = tot[i][3];
    }
    *(float4*)cp = o;
  }
}

// ---------------- logits = QW @ K^T  (K = QK[:,64:128], ld 128), K=64 ---------
__global__ __launch_bounds__(256) void logits_abt(const float* __restrict__ QW,
                                                  const float* __restrict__ QK,
                                                  float* __restrict__ L) {
  __shared__ float Aq[64][68];  // [c][m]
  __shared__ float Bk[64][68];  // [c][n]
  int t = threadIdx.x;
  int tx = t & 15, ty = t >> 4;
  int row0 = blockIdx.y * 64, col0 = blockIdx.x * 64;
#pragma unroll
  for (int v = 0; v < 16; ++v) {
    int idx = t + v * 256;
    int c = idx & 63, r = idx >> 6;
    Aq[c][r] = QW[(size_t)(row0 + r) * 64 + c];
    Bk[c][r] = QK[(size_t)(col0 + r) * 128 + 64 + c];
  }
  __syncthreads();
  float acc[4][4] = {};
#pragma unroll
  for (int c0 = 0; c0 < 64; ++c0) {
    float4 a = *(const float4*)&Aq[c0][ty * 4];
    float4 b = *(const float4*)&Bk[c0][tx * 4];
    float av[4] = {a.x, a.y, a.z, a.w};
    float bv[4] = {b.x, b.y, b.z, b.w};
#pragma unroll
    for (int i = 0; i < 4; ++i)
#pragma unroll
      for (int j = 0; j < 4; ++j)
        acc[i][j] = __builtin_fmaf(av[i], bv[j], acc[i][j]);
  }
#pragma unroll
  for (int i = 0; i < 4; ++i) {
    float4 o = {acc[i][0], acc[i][1], acc[i][2], acc[i][3]};
    *(float4*)&L[(size_t)(row0 + ty * 4 + i) * N_TOK + col0 + tx * 4] = o;
  }
}

// ---------------- exact top-p, bitwise-numpy fp32 semantics -------------------
// u32-key register-assisted bitonic sort (ties need no index tiebreak: equal
// values give identical exp/cumsum contributions; kept set recovered from the
// threshold key + tie counts, first-m ties in column order = ref's stable order).
// All float arithmetic (np_expf, pairwise sums, divisions, serial fp32 cumsum)
// is bit-identical to the previous passing version.
__global__ __launch_bounds__(512) void topp_exact(float* __restrict__ L) {
  __shared__ unsigned key[N_TOK];  // 16 KB (later reused to stage raw values)
  __shared__ float p[N_TOK];       // 16 KB
  __shared__ float sbuf[N_TOK];    // 16 KB
  __shared__ float fshare;
  __shared__ float mxs;
  __shared__ int kshare;
  __shared__ int ired[8];

  float* l = L + (size_t)blockIdx.x * N_TOK;
  int t = threadIdx.x;

  // 1) build descending-monotone u32 keys
  for (int i = t; i < N_TOK; i += 512) key[i] = desc_key(l[i]);
  __syncthreads();

  // 2a) k = 2,4,8 stages fully in registers (8-elem chunk per thread)
  {
    int base = t * 8;
    unsigned r[8];
    *(uint4*)&r[0] = *(const uint4*)&key[base];
    *(uint4*)&r[4] = *(const uint4*)&key[base + 4];
#pragma unroll
    for (int k = 2; k <= 8; k <<= 1)
#pragma unroll
      for (int j = 8; j > 0; j >>= 1) {
        if (j >= k) continue;
#pragma unroll
        for (int a = 0; a < 8; ++a) {
          int b = a ^ j;
          if (b > a) {
            bool asc = (((base + a) & k) == 0);
            unsigned x = r[a], y = r[b];
            if ((x > y) == asc) { r[a] = y; r[b] = x; }
          }
        }
      }
    *(uint4*)&key[base] = *(uint4*)&r[0];
    *(uint4*)&key[base + 4] = *(uint4*)&r[4];
  }
  __syncthreads();

  // 2b) k = 16..4096: j>=8 via LDS pair-processing, j<=4 in registers
  for (int k = 16; k <= N_TOK; k <<= 1) {
    for (int j = k >> 1; j >= 8; j >>= 1) {
      int jl = 31 - __clz(j);
#pragma unroll
      for (int it = 0; it < 4; ++it) {
        int q = it * 512 + t;
        int i = ((q >> jl) << (jl + 1)) | (q & (j - 1));
        int pa = i | j;
        bool asc = ((i & k) == 0);
        unsigned x = key[i], y = key[pa];
        bool sw = (x > y) == asc;
        key[i] = sw ? y : x;
        key[pa] = sw ? x : y;
      }
      __syncthreads();
    }
    {  // register round: j = 4,2,1 (direction uniform within 8-chunk for k>=16)
      int base = t * 8;
      bool asc = ((base & k) == 0);
      unsigned r[8];
      *(uint4*)&r[0] = *(const uint4*)&key[base];
      *(uint4*)&r[4] = *(const uint4*)&key[base + 4];
#pragma unroll
      for (int j = 4; j > 0; j >>= 1)
#pragma unroll
        for (int a = 0; a < 8; ++a) {
          int b = a ^ j;
          if (b > a) {
            unsigned x = r[a], y = r[b];
            if ((x > y) == asc) { r[a] = y; r[b] = x; }
          }
        }
      *(uint4*)&key[base] = *(uint4*)&r[0];
      *(uint4*)&key[base + 4] = *(uint4*)&r[4];
    }
    __syncthreads();
  }

  // 3) max + e by rank
  if (t == 0) mxs = desc_key_inv(key[0]);
  __syncthreads();
  float mx = mxs;
  for (int i = t; i < N_TOK; i += 512) p[i] = np_expf(desc_key_inv(key[i]) - mx);
  float tot = npPairwiseSum4096(p, &fshare);  // syncs internally

  // 4) probs = e / tot (fp32 division)
  for (int i = t; i < N_TOK; i += 512) p[i] = p[i] / tot;
  __syncthreads();

  // 5) strictly sequential fp32 cumsum; k = count(csum < 0.9f) + 1
  if (t == 0) {
    float c = 0.f;
    int cnt = 0;
    for (int j = 0; j < N_TOK; j += 4) {
      float4 q = *(const float4*)&p[j];
      c += q.x; cnt += (c < 0.9f) ? 1 : 0;
      c += q.y; cnt += (c < 0.9f) ? 1 : 0;
      c += q.z; cnt += (c < 0.9f) ? 1 : 0;
      c += q.w; cnt += (c < 0.9f) ? 1 : 0;
    }
    kshare = (cnt + 1 < N_TOK) ? cnt + 1 : N_TOK;
  }
  __syncthreads();
  int kcut = kshare;

  // 6) threshold key + tie bookkeeping
  unsigned kt = key[kcut - 1];
  int cg = 0, ce = 0;
  for (int i = t; i < N_TOK; i += 512) {
    cg += (key[i] < kt) ? 1 : 0;
    ce += (key[i] == kt) ? 1 : 0;
  }
  cg = blockSumI512(cg, ired);
  ce = blockSumI512(ce, ired);
  int m_keep = kcut - cg;          // tied elements kept (>=1)
  bool allties = (m_keep == ce);   // common case: all ties kept
  __syncthreads();                 // counts done before key[] reuse

  // 7) build kept-e scatter buffer (stage raw value bits into key[] for the
  //    rare partial-tie path)
  for (int i = t; i < N_TOK; i += 512) {
    float v = l[i];
    unsigned vk = desc_key(v);
    key[i] = __float_as_uint(v);
    bool keep = allties ? (vk <= kt) : (vk < kt);
    sbuf[i] = keep ? np_expf(v - mx) : 0.f;
  }
  __syncthreads();
  if (!allties && t == 0) {  // rare: keep only first m_keep ties in column order
    int taken = 0;
    for (int i = 0; i < N_TOK && taken < m_keep; ++i) {
      float v = __uint_as_float(key[i]);
      if (desc_key(v) == kt) { sbuf[i] = np_expf(v - mx); ++taken; }
    }
  }
  float denom = npPairwiseSum4096(sbuf, &fshare);  // syncs internally

  // 8) A row = sbuf / denom (fp32 division; zeros stay +0)
  for (int i = t; i < N_TOK; i += 512) l[i] = sbuf[i] / denom;
}

// ---------------- Xf = (T + Xf) * rs[row], vectorized float4 ------------------
__global__ __launch_bounds__(256) void xf_update(float* __restrict__ Xf,
                                                 const float* __restrict__ T,
                                                 const float* __restrict__ rs) {
  int idx = blockIdx.x * 256 + threadIdx.x;  // float4 index; total 1M
  int row = idx >> 8;
  float r = rs[row];
  float4 a = ((const float4*)T)[idx];
  float4 b = ((const float4*)Xf)[idx];
  float4 o;
  o.x = (a.x + b.x) * r; o.y = (a.y + b.y) * r;
  o.z = (a.z + b.z) * r; o.w = (a.w + b.w) * r;
  ((float4*)Xf)[idx] = o;
}

// ---------------- out = LayerNorm(X + Z) * gamma + beta  (Z lives in out) -----
__global__ __launch_bounds__(256) void ln_kernel(const float* __restrict__ X,
                                                 float* __restrict__ out,
                                                 const float* __restrict__ gamma,
                                                 const float* __restrict__ beta) {
  __shared__ float red[4];
  size_t base = (size_t)blockIdx.x * D_INF;
  int t = threadIdx.x;
  float y[4];
  float s = 0.f, ss = 0.f;
#pragma unroll
  for (int i = 0; i < 4; ++i) {
    int c = i * 256 + t;
    y[i] = X[base + c] + out[base + c];
    s += y[i];
    ss += y[i] * y[i];
  }
  s = blockSum(s, red);
  ss = blockSum(ss, red);
  float mean = s * (1.f / 1024.f);
  float var = ss * (1.f / 1024.f) - mean * mean;
  float rstd = rsqrtf(var + 1e-5f);
#pragma unroll
  for (int i = 0; i < 4; ++i) {
    int c = i * 256 + t;
    out[base + c] = (y[i] - mean) * rstd * gamma[c] + beta[c];
  }
}

// -----------------------------------------------------------------------------
extern "C" void kernel_launch(void* const* d_in, const int* in_sizes, int n_in,
                              void* d_out, int out_size, void* d_ws, size_t ws_size,
                              hipStream_t stream) {
  const float* X    = (const float*)d_in[0];
  const float* S    = (const float*)d_in[1];
  const float* W1   = (const float*)d_in[2];
  const float* W2   = (const float*)d_in[3];
  const float* W3   = (const float*)d_in[4];
  const float* U1_0 = (const float*)d_in[5];
  const float* U1_1 = (const float*)d_in[6];
  const float* U2_0 = (const float*)d_in[7];
  const float* U2_1 = (const float*)d_in[8];
  const float* gamma = (const float*)d_in[9];
  const float* beta  = (const float*)d_in[10];
  float* Z = (float*)d_out;  // Z accumulates in d_out; LN finalizes in place

  const size_t ND = (size_t)N_TOK * D_INF;   // 4M
  const size_t NN = (size_t)N_TOK * N_TOK;   // 16M
  float* Xf  = (float*)d_ws;
  float* Xa0 = Xf  + ND;
  float* Xa1 = Xa0 + ND;
  float* T   = Xa1 + ND;
  float* L   = T   + ND;                      // 16M
  float* QKb = L   + NN;                      // 4096x128
  float* QWb = QKb + (size_t)N_TOK * 128;     // 4096x64
  float* Wc  = QWb + (size_t)N_TOK * 64;      // 1024x128
  float* rs  = Wc  + (size_t)D_INF * 128;     // 4096

  hipMemcpyAsync(Xf, X, ND * sizeof(float), hipMemcpyDeviceToDevice, stream);
  rowsum_kernel<<<N_TOK, 256, 0, stream>>>(S, rs);
  wcat_kernel<<<D_INF, 128, 0, stream>>>(W1, W3, Wc);

  // ===== step 0 (Xa = X) =====
  gemm_tile<0><<<dim3(2, 64), 256, 0, stream>>>(X, Wc, QKb, N_TOK, 128, D_INF);
  qw_kernel<<<N_TOK / 4, 256, 0, stream>>>(QKb, W2, QWb);
  logits_abt<<<dim3(64, 64), 256, 0, stream>>>(QWb, QKb, L);
  topp_exact<<<N_TOK, 512, 0, stream>>>(L);                       // A1 in L
  gemm_tile<0><<<dim3(16, 64), 256, 0, stream>>>(S, Xf, T, N_TOK, D_INF, N_TOK);
  xf_update<<<4096, 256, 0, stream>>>(Xf, T, rs);
  gemm_tile<0><<<dim3(16, 64), 256, 0, stream>>>(L, X, Xa0, N_TOK, D_INF, N_TOK);
  gemm_tile<0><<<dim3(16, 64), 256, 0, stream>>>(Xf, U1_0, Z, N_TOK, D_INF, D_INF);
  gemm_tile<1><<<dim3(16, 64), 256, 0, stream>>>(Xa0, U2_0, Z, N_TOK, D_INF, D_INF);

  // ===== step 1 (Xa = Xa0) =====
  gemm_tile<0><<<dim3(2, 64), 256, 0, stream>>>(Xa0, Wc, QKb, N_TOK, 128, D_INF);
  qw_kernel<<<N_TOK / 4, 256, 0, stream>>>(QKb, W2, QWb);
  logits_abt<<<dim3(64, 64), 256, 0, stream>>>(QWb, QKb, L);
  topp_exact<<<N_TOK, 512, 0, stream>>>(L);                       // A2 in L
  gemm_tile<0><<<dim3(16, 64), 256, 0, stream>>>(S, Xf, T, N_TOK, D_INF, N_TOK);
  xf_update<<<4096, 256, 0, stream>>>(Xf, T, rs);
  gemm_tile<0><<<dim3(16, 64), 256, 0, stream>>>(L, Xa0, Xa1, N_TOK, D_INF, N_TOK);
  gemm_tile<1><<<dim3(16, 64), 256, 0, stream>>>(Xf, U1_1, Z, N_TOK, D_INF, D_INF);
  gemm_tile<1><<<dim3(16, 64), 256, 0, stream>>>(Xa1, U2_1, Z, N_TOK, D_INF, D_INF);

  ln_kernel<<<N_TOK, 256, 0, stream>>>(X, Z, gamma, beta);
}

// Round 10
// 3625.471 us; speedup vs baseline: 1.6516x; 1.1758x over previous
//
#include <hip/hip_runtime.h>
#include <cstddef>
#include <cmath>

#define N_TOK 4096
#define D_INF 1024
#define OB_Q 384  // OpenBLAS SGEMM_DEFAULT_Q for Haswell/ZEN (pypi-wheel on EPYC)

typedef unsigned long long u64;
typedef __attribute__((ext_vector_type(8))) short bf16x8;
typedef __attribute__((ext_vector_type(4))) float f32x4;

// ---------------- block reduction helpers -------------------------------------
__device__ __forceinline__ float blockSum(float x, float* red) {
#pragma unroll
  for (int o = 32; o; o >>= 1) x += __shfl_xor(x, o);
  __syncthreads();
  if ((threadIdx.x & 63) == 0) red[threadIdx.x >> 6] = x;
  __syncthreads();
  return (red[0] + red[1]) + (red[2] + red[3]);
}

__device__ __forceinline__ int blockSumI512(int x, int* red) {
#pragma unroll
  for (int o = 32; o; o >>= 1) x += __shfl_xor(x, o);
  __syncthreads();
  if ((threadIdx.x & 63) == 0) red[threadIdx.x >> 6] = x;
  __syncthreads();
  int s = 0;
#pragma unroll
  for (int w = 0; w < 8; ++w) s += red[w];
  return s;
}

// ---------------- numpy float32 exp, bitwise emulation ------------------------
__device__ __forceinline__ float np_expf(float x) {
  const float log2e = 1.44269504088896341f;  // 0x3FB8AA3B
  float q = __builtin_rintf(x * log2e);
  float r = __builtin_fmaf(q, -0.693359375f, x);        // Cody-Waite hi
  r = __builtin_fmaf(q, 2.12194440e-4f, r);             // Cody-Waite lo (-C2)
  float poly = 1.9875691500e-4f;
  poly = __builtin_fmaf(poly, r, 1.3981999507e-3f);
  poly = __builtin_fmaf(poly, r, 8.3334519073e-3f);
  poly = __builtin_fmaf(poly, r, 4.1665795894e-2f);
  poly = __builtin_fmaf(poly, r, 1.6666665459e-1f);
  poly = __builtin_fmaf(poly, r, 5.0000001201e-1f);
  float zz = r * r;                                     // rounded separately
  poly = __builtin_fmaf(poly, zz, r);
  poly = poly + 1.0f;
  return __builtin_ldexpf(poly, (int)q);                // exact 2^q scale
}

// ---------------- numpy pairwise_sum over 4096 floats in LDS ------------------
__device__ float npPairwiseSum4096(const float* __restrict__ buf, float* share) {
  int t = threadIdx.x;
  __syncthreads();  // buf fully written
  if (t < 32) {
    const float* a = buf + (t << 7);
    float r0 = a[0], r1 = a[1], r2 = a[2], r3 = a[3];
    float r4 = a[4], r5 = a[5], r6 = a[6], r7 = a[7];
    for (int i = 8; i < 128; i += 8) {
      r0 += a[i];     r1 += a[i + 1]; r2 += a[i + 2]; r3 += a[i + 3];
      r4 += a[i + 4]; r5 += a[i + 5]; r6 += a[i + 6]; r7 += a[i + 7];
    }
    float leaf = ((r0 + r1) + (r2 + r3)) + ((r4 + r5) + (r6 + r7));
    leaf += __shfl_xor(leaf, 1);
    leaf += __shfl_xor(leaf, 2);
    leaf += __shfl_xor(leaf, 4);
    leaf += __shfl_xor(leaf, 8);
    leaf += __shfl_xor(leaf, 16);
    if (t == 0) share[0] = leaf;
  }
  __syncthreads();
  return share[0];
}

// key transform: u32 monotone key, ascending key order == descending float order
__device__ __forceinline__ unsigned desc_key(float v) {
  unsigned u = __float_as_uint(v);
  unsigned m = (u & 0x80000000u) ? ~u : (u | 0x80000000u);
  return ~m;
}
__device__ __forceinline__ float desc_key_inv(unsigned k) {
  unsigned m = ~k;
  return __uint_as_float((m & 0x80000000u) ? (m ^ 0x80000000u) : ~m);
}

// LDS bank swizzle for key[]: flip 16B-line index (bits 2-4) by bits 5-7.
// Bits 0-1 untouched -> uint4 contiguity/alignment preserved.
__device__ __forceinline__ int KPHYS(int i) { return i ^ (((i >> 5) & 7) << 2); }

__device__ __forceinline__ uint4 u4min(uint4 a, uint4 b) {
  uint4 r;
  r.x = a.x < b.x ? a.x : b.x; r.y = a.y < b.y ? a.y : b.y;
  r.z = a.z < b.z ? a.z : b.z; r.w = a.w < b.w ? a.w : b.w;
  return r;
}
__device__ __forceinline__ uint4 u4max(uint4 a, uint4 b) {
  uint4 r;
  r.x = a.x < b.x ? b.x : a.x; r.y = a.y < b.y ? b.y : a.y;
  r.z = a.z < b.z ? b.z : a.z; r.w = a.w < b.w ? b.w : a.w;
  return r;
}

// fp32 -> bf16 round-to-nearest-even (bit trick)
__device__ __forceinline__ unsigned short f2bf(float f) {
  unsigned u = __float_as_uint(f);
  return (unsigned short)((u + 0x7FFFu + ((u >> 16) & 1u)) >> 16);
}

// ---------------- rowsum of S (+1 for identity), store reciprocal -------------
__global__ __launch_bounds__(256) void rowsum_kernel(const float* __restrict__ S,
                                                     float* __restrict__ rs) {
  __shared__ float red[4];
  const float* s = S + (size_t)blockIdx.x * N_TOK;
  float acc = 0.f;
  for (int j = threadIdx.x; j < N_TOK; j += 256) acc += s[j];
  acc = blockSum(acc, red);
  if (threadIdx.x == 0) rs[blockIdx.x] = 1.0f / fmaxf(acc + 1.0f, 1e-12f);
}

// ---------------- Wcat = [W1 | W3]  (1024 x 128) ------------------------------
__global__ void wcat_kernel(const float* __restrict__ W1,
                            const float* __restrict__ W3, float* __restrict__ Wc) {
  int r = blockIdx.x;
  int c = threadIdx.x;
  Wc[r * 128 + c] = (c < 64) ? W1[r * 64 + c] : W3[r * 64 + (c - 64)];
}

// ---------------- QW = Q @ W2 (Q = QK[:,0:64], ld 128) ------------------------
__global__ __launch_bounds__(256) void qw_kernel(const float* __restrict__ QK,
                                                 const float* __restrict__ W2,
                                                 float* __restrict__ QW) {
  __shared__ float w[64][65];
  int t = threadIdx.x;
#pragma unroll
  for (int v = 0; v < 16; ++v) {
    int idx = t + v * 256;
    w[idx >> 6][idx & 63] = W2[idx];
  }
  __syncthreads();
  int row = blockIdx.x * 4 + (t >> 6);
  int c = t & 63;
  const float* q = QK + (size_t)row * 128;
  float acc = 0.f;
#pragma unroll
  for (int k = 0; k < 64; ++k) acc = __builtin_fmaf(q[k], w[k][c], acc);
  QW[(size_t)row * 64 + c] = acc;
}

// ---------------- OpenBLAS kc-chunk step (level3.c balanced tail) -------------
__device__ __forceinline__ int ob_step(int rem) {
  if (rem >= 2 * OB_Q) return OB_Q;
  if (rem > OB_Q) return ((rem / 2) + 15) & ~15;
  return rem;
}

// ---------------- EXACT fp32 tiled GEMM (OpenBLAS-bitwise) --------------------
template <int BETA>
__global__ __launch_bounds__(256) void gemm_tile(const float* __restrict__ A,
                                                 const float* __restrict__ B,
                                                 float* __restrict__ C,
                                                 int M, int N, int K) {
  __shared__ float As[16][68];  // [k][m]
  __shared__ float Bs[16][68];  // [k][n]
  int t = threadIdx.x;
  int tx = t & 15, ty = t >> 4;
  int row0 = blockIdx.y * 64, col0 = blockIdx.x * 64;
  float tot[4][4] = {};
  float acc[4][4] = {};
  int next_b = ob_step(K);
  for (int k0 = 0; k0 < K; k0 += 16) {
    if (k0 == next_b) {
#pragma unroll
      for (int i = 0; i < 4; ++i)
#pragma unroll
        for (int j = 0; j < 4; ++j) { tot[i][j] += acc[i][j]; acc[i][j] = 0.f; }
      next_b = k0 + ob_step(K - k0);
    }
#pragma unroll
    for (int v = 0; v < 4; ++v) {
      int idx = t + v * 256;
      int r = idx >> 4, c = idx & 15;
      As[c][r] = A[(size_t)(row0 + r) * K + k0 + c];
    }
#pragma unroll
    for (int v = 0; v < 4; ++v) {
      int idx = t + v * 256;
      int r = idx >> 6, c = idx & 63;
      Bs[r][c] = B[(size_t)(k0 + r) * N + col0 + c];
    }
    __syncthreads();
#pragma unroll
    for (int kk = 0; kk < 16; ++kk) {
      float4 a = *(const float4*)&As[kk][ty * 4];
      float4 b = *(const float4*)&Bs[kk][tx * 4];
      float av[4] = {a.x, a.y, a.z, a.w};
      float bv[4] = {b.x, b.y, b.z, b.w};
#pragma unroll
      for (int i = 0; i < 4; ++i)
#pragma unroll
        for (int j = 0; j < 4; ++j)
          acc[i][j] = __builtin_fmaf(av[i], bv[j], acc[i][j]);
    }
    __syncthreads();
  }
#pragma unroll
  for (int i = 0; i < 4; ++i)
#pragma unroll
    for (int j = 0; j < 4; ++j) tot[i][j] += acc[i][j];
#pragma unroll
  for (int i = 0; i < 4; ++i) {
    float* cp = &C[(size_t)(row0 + ty * 4 + i) * N + col0 + tx * 4];
    float4 o;
    if (BETA) {
      float4 old = *(const float4*)cp;
      o.x = old.x + acc[i][0] + tot[i][0] - acc[i][0];  // keep simple below
      o.x = old.x + tot[i][0]; o.y = old.y + tot[i][1];
      o.z = old.z + tot[i][2]; o.w = old.w + tot[i][3];
    } else {
      o.x = tot[i][0]; o.y = tot[i][1]; o.z = tot[i][2]; o.w = tot[i][3];
    }
    *(float4*)cp = o;
  }
}

// ---------------- bf16 MFMA GEMM for VALUE-path (fp32 in/out) -----------------
// 128x128 tile, BK=32, 256 threads = 4 waves (2x2), each wave 64x64 = 4x4
// mfma_f32_16x16x32_bf16 fragments. A,B read fp32 from global, converted to
// bf16 (RNE) during LDS staging. LDS [row][k] bf16 with byte^=((row>>1)&3)<<4
// swizzle (ushort-index ^ ((row>>1)&3)<<3).
template <int BETA>
__global__ __launch_bounds__(256) void gemm_bf16(const float* __restrict__ A,
                                                 const float* __restrict__ B,
                                                 float* __restrict__ C,
                                                 int M, int N, int K) {
  __shared__ unsigned short As[128 * 32];  // [m][k]
  __shared__ unsigned short Bs[128 * 32];  // [n][k]
  const int t = threadIdx.x;
  const int l = t & 63, w = t >> 6, wr = w >> 1, wc = w & 1;
  const int m0 = blockIdx.y * 128, n0 = blockIdx.x * 128;

  f32x4 acc[4][4];
#pragma unroll
  for (int i = 0; i < 4; ++i)
#pragma unroll
    for (int j = 0; j < 4; ++j)
#pragma unroll
      for (int r = 0; r < 4; ++r) acc[i][j][r] = 0.f;

  const int argp = t >> 3;          // 0..31 : A row-group
  const int acc4 = (t & 7) * 4;     // 0..28 : A k-offset
  const int bkb = t >> 5;           // 0..7  : B k-block (4 rows)
  const int bnb = t & 31;           // 0..31 : B n-block (4 cols)

  for (int k0 = 0; k0 < K; k0 += 32) {
    // ---- stage A: 128x32 ----
#pragma unroll
    for (int u = 0; u < 4; ++u) {
      int row = argp * 4 + u;
      float4 v = *(const float4*)&A[(size_t)(m0 + row) * K + k0 + acc4];
      ushort4 h;
      h.x = f2bf(v.x); h.y = f2bf(v.y); h.z = f2bf(v.z); h.w = f2bf(v.w);
      int idx = (row * 32 + acc4) ^ (((row >> 1) & 3) << 3);
      *(ushort4*)&As[idx] = h;
    }
    // ---- stage B: 32x128, transposed to [n][k] via 4x4 register block ----
    {
      float4 r0 = *(const float4*)&B[(size_t)(k0 + bkb * 4 + 0) * N + n0 + bnb * 4];
      float4 r1 = *(const float4*)&B[(size_t)(k0 + bkb * 4 + 1) * N + n0 + bnb * 4];
      float4 r2 = *(const float4*)&B[(size_t)(k0 + bkb * 4 + 2) * N + n0 + bnb * 4];
      float4 r3 = *(const float4*)&B[(size_t)(k0 + bkb * 4 + 3) * N + n0 + bnb * 4];
      float c0[4] = {r0.x, r0.y, r0.z, r0.w};
      float c1[4] = {r1.x, r1.y, r1.z, r1.w};
      float c2[4] = {r2.x, r2.y, r2.z, r2.w};
      float c3[4] = {r3.x, r3.y, r3.z, r3.w};
#pragma unroll
      for (int u = 0; u < 4; ++u) {
        int nrow = bnb * 4 + u;
        ushort4 h;
        h.x = f2bf(c0[u]); h.y = f2bf(c1[u]); h.z = f2bf(c2[u]); h.w = f2bf(c3[u]);
        int idx = (nrow * 32 + bkb * 4) ^ (((nrow >> 1) & 3) << 3);
        *(ushort4*)&Bs[idx] = h;
      }
    }
    __syncthreads();
    // ---- compute: 16 MFMA per wave ----
    bf16x8 af[4], bf[4];
    const int kseg = (l >> 4) * 8;
#pragma unroll
    for (int fr = 0; fr < 4; ++fr) {
      int row = wr * 64 + fr * 16 + (l & 15);
      int idx = (row * 32 + kseg) ^ (((row >> 1) & 3) << 3);
      af[fr] = *(const bf16x8*)&As[idx];
    }
#pragma unroll
    for (int fc = 0; fc < 4; ++fc) {
      int nrow = wc * 64 + fc * 16 + (l & 15);
      int idx = (nrow * 32 + kseg) ^ (((nrow >> 1) & 3) << 3);
      bf[fc] = *(const bf16x8*)&Bs[idx];
    }
#pragma unroll
    for (int fr = 0; fr < 4; ++fr)
#pragma unroll
      for (int fc = 0; fc < 4; ++fc)
        acc[fr][fc] = __builtin_amdgcn_mfma_f32_16x16x32_bf16(af[fr], bf[fc],
                                                              acc[fr][fc], 0, 0, 0);
    __syncthreads();
  }
  // ---- epilogue: D lane layout col=l&15, row=(l>>4)*4+reg ----
#pragma unroll
  for (int fr = 0; fr < 4; ++fr) {
#pragma unroll
    for (int fc = 0; fc < 4; ++fc) {
      int rbase = m0 + wr * 64 + fr * 16 + ((l >> 4) << 2);
      int col = n0 + wc * 64 + fc * 16 + (l & 15);
#pragma unroll
      for (int r = 0; r < 4; ++r) {
        size_t off = (size_t)(rbase + r) * N + col;
        float v = acc[fr][fc][r];
        C[off] = BETA ? (C[off] + v) : v;
      }
    }
  }
}

// ---------------- logits = QW @ K^T  (K = QK[:,64:128], ld 128), K=64 ---------
__global__ __launch_bounds__(256) void logits_abt(const float* __restrict__ QW,
                                                  const float* __restrict__ QK,
                                                  float* __restrict__ L) {
  __shared__ float Aq[64][68];
  __shared__ float Bk[64][68];
  int t = threadIdx.x;
  int tx = t & 15, ty = t >> 4;
  int row0 = blockIdx.y * 64, col0 = blockIdx.x * 64;
#pragma unroll
  for (int v = 0; v < 16; ++v) {
    int idx = t + v * 256;
    int c = idx & 63, r = idx >> 6;
    Aq[c][r] = QW[(size_t)(row0 + r) * 64 + c];
    Bk[c][r] = QK[(size_t)(col0 + r) * 128 + 64 + c];
  }
  __syncthreads();
  float acc[4][4] = {};
#pragma unroll
  for (int c0 = 0; c0 < 64; ++c0) {
    float4 a = *(const float4*)&Aq[c0][ty * 4];
    float4 b = *(const float4*)&Bk[c0][tx * 4];
    float av[4] = {a.x, a.y, a.z, a.w};
    float bv[4] = {b.x, b.y, b.z, b.w};
#pragma unroll
    for (int i = 0; i < 4; ++i)
#pragma unroll
      for (int j = 0; j < 4; ++j)
        acc[i][j] = __builtin_fmaf(av[i], bv[j], acc[i][j]);
  }
#pragma unroll
  for (int i = 0; i < 4; ++i) {
    float4 o = {acc[i][0], acc[i][1], acc[i][2], acc[i][3]};
    *(float4*)&L[(size_t)(row0 + ty * 4 + i) * N_TOK + col0 + tx * 4] = o;
  }
}

// ---------------- exact top-p, bitwise-numpy fp32 semantics -------------------
// Sorted-values bitonic (u32 keys, swizzled LDS, uint4 pair-steps + register
// sub-networks). All observable float arithmetic bit-identical to R8/R9.
__global__ __launch_bounds__(512) void topp_exact(float* __restrict__ L) {
  __shared__ unsigned key[N_TOK];  // swizzled via KPHYS
  __shared__ float p[N_TOK];
  __shared__ float sbuf[N_TOK];
  __shared__ float fshare;
  __shared__ float mxs;
  __shared__ int kshare;
  __shared__ int ired[8];

  float* l = L + (size_t)blockIdx.x * N_TOK;
  int t = threadIdx.x;

  // 1) build keys
  for (int i = t; i < N_TOK; i += 512) key[KPHYS(i)] = desc_key(l[i]);
  __syncthreads();

  // 2a) k = 2,4,8 fully in registers (8-elem contiguous chunk per thread)
  {
    int base = t * 8;
    unsigned r[8];
    *(uint4*)&r[0] = *(const uint4*)&key[KPHYS(base)];
    *(uint4*)&r[4] = *(const uint4*)&key[KPHYS(base + 4)];
#pragma unroll
    for (int k = 2; k <= 8; k <<= 1)
#pragma unroll
      for (int j = 4; j > 0; j >>= 1) {
        if (j >= k) continue;
#pragma unroll
        for (int a = 0; a < 8; ++a) {
          int b = a ^ j;
          if (b > a) {
            bool asc = (((base + a) & k) == 0);
            unsigned x = r[a], y = r[b];
            if ((x > y) == asc) { r[a] = y; r[b] = x; }
          }
        }
      }
    *(uint4*)&key[KPHYS(base)] = *(uint4*)&r[0];
    *(uint4*)&key[KPHYS(base + 4)] = *(uint4*)&r[4];
  }
  __syncthreads();

  // 2b) k = 16..4096: j>=8 via uint4 pair-steps, j<=4 in registers
  for (int k = 16; k <= N_TOK; k <<= 1) {
    for (int j = k >> 1; j >= 8; j >>= 1) {
      int jl = 31 - __clz(j);
      int q = t * 4;  // 4 contiguous pairs; 512*4 = 2048 pairs = all
      int i0 = ((q >> jl) << (jl + 1)) | (q & (j - 1));
      bool asc = ((i0 & k) == 0);
      uint4 x = *(const uint4*)&key[KPHYS(i0)];
      uint4 y = *(const uint4*)&key[KPHYS(i0 + j)];
      uint4 mn = u4min(x, y), mx = u4max(x, y);
      *(uint4*)&key[KPHYS(i0)] = asc ? mn : mx;
      *(uint4*)&key[KPHYS(i0 + j)] = asc ? mx : mn;
      __syncthreads();
    }
    {  // register round j = 4,2,1 (direction uniform per 8-chunk for k>=16)
      int base = t * 8;
      bool asc = ((base & k) == 0);
      unsigned r[8];
      *(uint4*)&r[0] = *(const uint4*)&key[KPHYS(base)];
      *(uint4*)&r[4] = *(const uint4*)&key[KPHYS(base + 4)];
#pragma unroll
      for (int j = 4; j > 0; j >>= 1)
#pragma unroll
        for (int a = 0; a < 8; ++a) {
          int b = a ^ j;
          if (b > a) {
            unsigned x = r[a], y = r[b];
            if ((x > y) == asc) { r[a] = y; r[b] = x; }
          }
        }
      *(uint4*)&key[KPHYS(base)] = *(uint4*)&r[0];
      *(uint4*)&key[KPHYS(base + 4)] = *(uint4*)&r[4];
    }
    __syncthreads();
  }

  // 3) max + e by rank
  if (t == 0) mxs = desc_key_inv(key[KPHYS(0)]);
  __syncthreads();
  float mx = mxs;
  for (int i = t; i < N_TOK; i += 512)
    p[i] = np_expf(desc_key_inv(key[KPHYS(i)]) - mx);
  float tot = npPairwiseSum4096(p, &fshare);  // syncs internally

  // 4) probs = e / tot
  for (int i = t; i < N_TOK; i += 512) p[i] = p[i] / tot;
  __syncthreads();

  // 5) strictly sequential fp32 cumsum; k = count(csum < 0.9f) + 1
  if (t == 0) {
    float c = 0.f;
    int cnt = 0;
    for (int j = 0; j < N_TOK; j += 4) {
      float4 q = *(const float4*)&p[j];
      c += q.x; cnt += (c < 0.9f) ? 1 : 0;
      c += q.y; cnt += (c < 0.9f) ? 1 : 0;
      c += q.z; cnt += (c < 0.9f) ? 1 : 0;
      c += q.w; cnt += (c < 0.9f) ? 1 : 0;
    }
    kshare = (cnt + 1 < N_TOK) ? cnt + 1 : N_TOK;
  }
  __syncthreads();
  int kcut = kshare;

  // 6) threshold key + tie bookkeeping
  unsigned kt = key[KPHYS(kcut - 1)];
  int cg = 0, ce = 0;
  for (int i = t; i < N_TOK; i += 512) {
    unsigned kv = key[KPHYS(i)];
    cg += (kv < kt) ? 1 : 0;
    ce += (kv == kt) ? 1 : 0;
  }
  cg = blockSumI512(cg, ired);
  ce = blockSumI512(ce, ired);
  int m_keep = kcut - cg;
  bool allties = (m_keep == ce);
  __syncthreads();

  // 7) kept-e scatter (stage raw value bits into key[] for rare partial ties)
  for (int i = t; i < N_TOK; i += 512) {
    float v = l[i];
    unsigned vk = desc_key(v);
    key[KPHYS(i)] = __float_as_uint(v);
    bool keep = allties ? (vk <= kt) : (vk < kt);
    sbuf[i] = keep ? np_expf(v - mx) : 0.f;
  }
  __syncthreads();
  if (!allties && t == 0) {
    int taken = 0;
    for (int i = 0; i < N_TOK && taken < m_keep; ++i) {
      float v = __uint_as_float(key[KPHYS(i)]);
      if (desc_key(v) == kt) { sbuf[i] = np_expf(v - mx); ++taken; }
    }
  }
  float denom = npPairwiseSum4096(sbuf, &fshare);  // syncs internally

  // 8) A row = sbuf / denom
  for (int i = t; i < N_TOK; i += 512) l[i] = sbuf[i] / denom;
}

// ---------------- Xf = (T + Xf) * rs[row], vectorized float4 ------------------
__global__ __launch_bounds__(256) void xf_update(float* __restrict__ Xf,
                                                 const float* __restrict__ T,
                                                 const float* __restrict__ rs) {
  int idx = blockIdx.x * 256 + threadIdx.x;
  int row = idx >> 8;
  float r = rs[row];
  float4 a = ((const float4*)T)[idx];
  float4 b = ((const float4*)Xf)[idx];
  float4 o;
  o.x = (a.x + b.x) * r; o.y = (a.y + b.y) * r;
  o.z = (a.z + b.z) * r; o.w = (a.w + b.w) * r;
  ((float4*)Xf)[idx] = o;
}

// ---------------- out = LayerNorm(X + Z) * gamma + beta  (Z lives in out) -----
__global__ __launch_bounds__(256) void ln_kernel(const float* __restrict__ X,
                                                 float* __restrict__ out,
                                                 const float* __restrict__ gamma,
                                                 const float* __restrict__ beta) {
  __shared__ float red[4];
  size_t base = (size_t)blockIdx.x * D_INF;
  int t = threadIdx.x;
  float y[4];
  float s = 0.f, ss = 0.f;
#pragma unroll
  for (int i = 0; i < 4; ++i) {
    int c = i * 256 + t;
    y[i] = X[base + c] + out[base + c];
    s += y[i];
    ss += y[i] * y[i];
  }
  s = blockSum(s, red);
  ss = blockSum(ss, red);
  float mean = s * (1.f / 1024.f);
  float var = ss * (1.f / 1024.f) - mean * mean;
  float rstd = rsqrtf(var + 1e-5f);
#pragma unroll
  for (int i = 0; i < 4; ++i) {
    int c = i * 256 + t;
    out[base + c] = (y[i] - mean) * rstd * gamma[c] + beta[c];
  }
}

// -----------------------------------------------------------------------------
extern "C" void kernel_launch(void* const* d_in, const int* in_sizes, int n_in,
                              void* d_out, int out_size, void* d_ws, size_t ws_size,
                              hipStream_t stream) {
  const float* X    = (const float*)d_in[0];
  const float* S    = (const float*)d_in[1];
  const float* W1   = (const float*)d_in[2];
  const float* W2   = (const float*)d_in[3];
  const float* W3   = (const float*)d_in[4];
  const float* U1_0 = (const float*)d_in[5];
  const float* U1_1 = (const float*)d_in[6];
  const float* U2_0 = (const float*)d_in[7];
  const float* U2_1 = (const float*)d_in[8];
  const float* gamma = (const float*)d_in[9];
  const float* beta  = (const float*)d_in[10];
  float* Z = (float*)d_out;

  const size_t ND = (size_t)N_TOK * D_INF;   // 4M
  const size_t NN = (size_t)N_TOK * N_TOK;   // 16M
  float* Xf  = (float*)d_ws;
  float* Xa0 = Xf  + ND;
  float* Xa1 = Xa0 + ND;
  float* T   = Xa1 + ND;
  float* L   = T   + ND;                      // 16M
  float* QKb = L   + NN;
  float* QWb = QKb + (size_t)N_TOK * 128;
  float* Wc  = QWb + (size_t)N_TOK * 64;
  float* rs  = Wc  + (size_t)D_INF * 128;

  hipMemcpyAsync(Xf, X, ND * sizeof(float), hipMemcpyDeviceToDevice, stream);
  rowsum_kernel<<<N_TOK, 256, 0, stream>>>(S, rs);
  wcat_kernel<<<D_INF, 128, 0, stream>>>(W1, W3, Wc);

  dim3 g128(D_INF / 128, N_TOK / 128);  // (8, 32) for M=4096, N=1024

  // ===== step 0 (Xa = X) =====
  gemm_tile<0><<<dim3(2, 64), 256, 0, stream>>>(X, Wc, QKb, N_TOK, 128, D_INF);
  qw_kernel<<<N_TOK / 4, 256, 0, stream>>>(QKb, W2, QWb);
  logits_abt<<<dim3(64, 64), 256, 0, stream>>>(QWb, QKb, L);
  topp_exact<<<N_TOK, 512, 0, stream>>>(L);                       // A1 in L
  gemm_bf16<0><<<g128, 256, 0, stream>>>(S, Xf, T, N_TOK, D_INF, N_TOK);
  xf_update<<<4096, 256, 0, stream>>>(Xf, T, rs);
  // Xa0 = A1 @ X — EXACT fp32 (feeds step-1 logits / decision path)
  gemm_tile<0><<<dim3(16, 64), 256, 0, stream>>>(L, X, Xa0, N_TOK, D_INF, N_TOK);
  gemm_bf16<0><<<g128, 256, 0, stream>>>(Xf, U1_0, Z, N_TOK, D_INF, D_INF);
  gemm_bf16<1><<<g128, 256, 0, stream>>>(Xa0, U2_0, Z, N_TOK, D_INF, D_INF);

  // ===== step 1 (Xa = Xa0) =====
  gemm_tile<0><<<dim3(2, 64), 256, 0, stream>>>(Xa0, Wc, QKb, N_TOK, 128, D_INF);
  qw_kernel<<<N_TOK / 4, 256, 0, stream>>>(QKb, W2, QWb);
  logits_abt<<<dim3(64, 64), 256, 0, stream>>>(QWb, QKb, L);
  topp_exact<<<N_TOK, 512, 0, stream>>>(L);                       // A2 in L
  gemm_bf16<0><<<g128, 256, 0, stream>>>(S, Xf, T, N_TOK, D_INF, N_TOK);
  xf_update<<<4096, 256, 0, stream>>>(Xf, T, rs);
  gemm_bf16<0><<<g128, 256, 0, stream>>>(L, Xa0, Xa1, N_TOK, D_INF, N_TOK);
  gemm_bf16<1><<<g128, 256, 0, stream>>>(Xf, U1_1, Z, N_TOK, D_INF, D_INF);
  gemm_bf16<1><<<g128, 256, 0, stream>>>(Xa1, U2_1, Z, N_TOK, D_INF, D_INF);

  ln_kernel<<<N_TOK, 256, 0, stream>>>(X, Z, gamma, beta);
}

// Round 12
// 2124.692 us; speedup vs baseline: 2.8182x; 1.7064x over previous
//
#include <hip/hip_runtime.h>
#include <cstddef>
#include <cmath>

#define N_TOK 4096
#define D_INF 1024
#define OB_Q 384  // OpenBLAS SGEMM_DEFAULT_Q for Haswell/ZEN (pypi-wheel on EPYC)

typedef unsigned long long u64;
typedef __attribute__((ext_vector_type(8))) short bf16x8;
typedef __attribute__((ext_vector_type(4))) float f32x4;

// ---------------- block reduction helpers -------------------------------------
__device__ __forceinline__ float blockSum(float x, float* red) {
#pragma unroll
  for (int o = 32; o; o >>= 1) x += __shfl_xor(x, o);
  __syncthreads();
  if ((threadIdx.x & 63) == 0) red[threadIdx.x >> 6] = x;
  __syncthreads();
  return (red[0] + red[1]) + (red[2] + red[3]);
}

__device__ __forceinline__ int blockSumI512(int x, int* red) {
#pragma unroll
  for (int o = 32; o; o >>= 1) x += __shfl_xor(x, o);
  __syncthreads();
  if ((threadIdx.x & 63) == 0) red[threadIdx.x >> 6] = x;
  __syncthreads();
  int s = 0;
#pragma unroll
  for (int w = 0; w < 8; ++w) s += red[w];
  return s;
}

// ---------------- numpy float32 exp, bitwise emulation ------------------------
__device__ __forceinline__ float np_expf(float x) {
  const float log2e = 1.44269504088896341f;  // 0x3FB8AA3B
  float q = __builtin_rintf(x * log2e);
  float r = __builtin_fmaf(q, -0.693359375f, x);        // Cody-Waite hi
  r = __builtin_fmaf(q, 2.12194440e-4f, r);             // Cody-Waite lo (-C2)
  float poly = 1.9875691500e-4f;
  poly = __builtin_fmaf(poly, r, 1.3981999507e-3f);
  poly = __builtin_fmaf(poly, r, 8.3334519073e-3f);
  poly = __builtin_fmaf(poly, r, 4.1665795894e-2f);
  poly = __builtin_fmaf(poly, r, 1.6666665459e-1f);
  poly = __builtin_fmaf(poly, r, 5.0000001201e-1f);
  float zz = r * r;                                     // rounded separately
  poly = __builtin_fmaf(poly, zz, r);
  poly = poly + 1.0f;
  return __builtin_ldexpf(poly, (int)q);                // exact 2^q scale
}

// ---------------- numpy pairwise_sum over 4096 floats in LDS ------------------
__device__ float npPairwiseSum4096(const float* __restrict__ buf, float* share) {
  int t = threadIdx.x;
  __syncthreads();  // buf fully written
  if (t < 32) {
    const float* a = buf + (t << 7);
    float r0 = a[0], r1 = a[1], r2 = a[2], r3 = a[3];
    float r4 = a[4], r5 = a[5], r6 = a[6], r7 = a[7];
    for (int i = 8; i < 128; i += 8) {
      r0 += a[i];     r1 += a[i + 1]; r2 += a[i + 2]; r3 += a[i + 3];
      r4 += a[i + 4]; r5 += a[i + 5]; r6 += a[i + 6]; r7 += a[i + 7];
    }
    float leaf = ((r0 + r1) + (r2 + r3)) + ((r4 + r5) + (r6 + r7));
    leaf += __shfl_xor(leaf, 1);
    leaf += __shfl_xor(leaf, 2);
    leaf += __shfl_xor(leaf, 4);
    leaf += __shfl_xor(leaf, 8);
    leaf += __shfl_xor(leaf, 16);
    if (t == 0) share[0] = leaf;
  }
  __syncthreads();
  return share[0];
}

// key transform: u32 monotone key, ascending key order == descending float order
__device__ __forceinline__ unsigned desc_key(float v) {
  unsigned u = __float_as_uint(v);
  unsigned m = (u & 0x80000000u) ? ~u : (u | 0x80000000u);
  return ~m;
}
__device__ __forceinline__ float desc_key_inv(unsigned k) {
  unsigned m = ~k;
  return __uint_as_float((m & 0x80000000u) ? (m ^ 0x80000000u) : ~m);
}

// fp32 -> bf16 round-to-nearest-even (bit trick)
__device__ __forceinline__ unsigned short f2bf(float f) {
  unsigned u = __float_as_uint(f);
  return (unsigned short)((u + 0x7FFFu + ((u >> 16) & 1u)) >> 16);
}

// ---------------- rowsum of S (+1 for identity), store reciprocal -------------
__global__ __launch_bounds__(256) void rowsum_kernel(const float* __restrict__ S,
                                                     float* __restrict__ rs) {
  __shared__ float red[4];
  const float* s = S + (size_t)blockIdx.x * N_TOK;
  float acc = 0.f;
  for (int j = threadIdx.x; j < N_TOK; j += 256) acc += s[j];
  acc = blockSum(acc, red);
  if (threadIdx.x == 0) rs[blockIdx.x] = 1.0f / fmaxf(acc + 1.0f, 1e-12f);
}

// ---------------- Wcat = [W1 | W3]  (1024 x 128) ------------------------------
__global__ void wcat_kernel(const float* __restrict__ W1,
                            const float* __restrict__ W3, float* __restrict__ Wc) {
  int r = blockIdx.x;
  int c = threadIdx.x;
  Wc[r * 128 + c] = (c < 64) ? W1[r * 64 + c] : W3[r * 64 + (c - 64)];
}

// ---------------- QW = Q @ W2 (Q = QK[:,0:64], ld 128) ------------------------
__global__ __launch_bounds__(256) void qw_kernel(const float* __restrict__ QK,
                                                 const float* __restrict__ W2,
                                                 float* __restrict__ QW) {
  __shared__ float w[64][65];
  int t = threadIdx.x;
#pragma unroll
  for (int v = 0; v < 16; ++v) {
    int idx = t + v * 256;
    w[idx >> 6][idx & 63] = W2[idx];
  }
  __syncthreads();
  int row = blockIdx.x * 4 + (t >> 6);
  int c = t & 63;
  const float* q = QK + (size_t)row * 128;
  float acc = 0.f;
#pragma unroll
  for (int k = 0; k < 64; ++k) acc = __builtin_fmaf(q[k], w[k][c], acc);
  QW[(size_t)row * 64 + c] = acc;
}

// ---------------- OpenBLAS kc-chunk step (level3.c balanced tail) -------------
__device__ __forceinline__ int ob_step(int rem) {
  if (rem >= 2 * OB_Q) return OB_Q;
  if (rem > OB_Q) return ((rem / 2) + 15) & ~15;
  return rem;
}

// ---------------- EXACT fp32 tiled GEMM (OpenBLAS-bitwise) --------------------
template <int BETA>
__global__ __launch_bounds__(256) void gemm_tile(const float* __restrict__ A,
                                                 const float* __restrict__ B,
                                                 float* __restrict__ C,
                                                 int M, int N, int K) {
  __shared__ float As[16][68];  // [k][m]
  __shared__ float Bs[16][68];  // [k][n]
  int t = threadIdx.x;
  int tx = t & 15, ty = t >> 4;
  int row0 = blockIdx.y * 64, col0 = blockIdx.x * 64;
  float tot[4][4] = {};
  float acc[4][4] = {};
  int next_b = ob_step(K);
  for (int k0 = 0; k0 < K; k0 += 16) {
    if (k0 == next_b) {
#pragma unroll
      for (int i = 0; i < 4; ++i)
#pragma unroll
        for (int j = 0; j < 4; ++j) { tot[i][j] += acc[i][j]; acc[i][j] = 0.f; }
      next_b = k0 + ob_step(K - k0);
    }
#pragma unroll
    for (int v = 0; v < 4; ++v) {
      int idx = t + v * 256;
      int r = idx >> 4, c = idx & 15;
      As[c][r] = A[(size_t)(row0 + r) * K + k0 + c];
    }
#pragma unroll
    for (int v = 0; v < 4; ++v) {
      int idx = t + v * 256;
      int r = idx >> 6, c = idx & 63;
      Bs[r][c] = B[(size_t)(k0 + r) * N + col0 + c];
    }
    __syncthreads();
#pragma unroll
    for (int kk = 0; kk < 16; ++kk) {
      float4 a = *(const float4*)&As[kk][ty * 4];
      float4 b = *(const float4*)&Bs[kk][tx * 4];
      float av[4] = {a.x, a.y, a.z, a.w};
      float bv[4] = {b.x, b.y, b.z, b.w};
#pragma unroll
      for (int i = 0; i < 4; ++i)
#pragma unroll
        for (int j = 0; j < 4; ++j)
          acc[i][j] = __builtin_fmaf(av[i], bv[j], acc[i][j]);
    }
    __syncthreads();
  }
#pragma unroll
  for (int i = 0; i < 4; ++i)
#pragma unroll
    for (int j = 0; j < 4; ++j) tot[i][j] += acc[i][j];
#pragma unroll
  for (int i = 0; i < 4; ++i) {
    float* cp = &C[(size_t)(row0 + ty * 4 + i) * N + col0 + tx * 4];
    float4 o;
    if (BETA) {
      float4 old = *(const float4*)cp;
      o.x = old.x + tot[i][0]; o.y = old.y + tot[i][1];
      o.z = old.z + tot[i][2]; o.w = old.w + tot[i][3];
    } else {
      o.x = tot[i][0]; o.y = tot[i][1]; o.z = tot[i][2]; o.w = tot[i][3];
    }
    *(float4*)cp = o;
  }
}

// ---------------- EXACT sparse x dense: C = A @ X, A = top-p rows -------------
// Skipping a==0 terms is bitwise-identical (fl(c + 0*b) = c; acc never -0);
// kc fold boundaries are positional (same ob_step walk as gemm_tile).
__global__ __launch_bounds__(256) void spmm_exact(const float* __restrict__ A,
                                                  const float* __restrict__ X,
                                                  float* __restrict__ C) {
  __shared__ unsigned short idxs[N_TOK];  // 8 KB
  __shared__ int wq[4];
  int t = threadIdx.x;
  int lane = t & 63, w = t >> 6;
  int row = blockIdx.x;
  const float* a = A + (size_t)row * N_TOK;

  int base = t * 16;
  int c0 = 0;
#pragma unroll
  for (int u = 0; u < 16; ++u) c0 += (a[base + u] != 0.f) ? 1 : 0;
  int incl = c0;
#pragma unroll
  for (int d = 1; d < 64; d <<= 1) {
    int up = __shfl_up(incl, d);
    if (lane >= d) incl += up;
  }
  if (lane == 63) wq[w] = incl;
  __syncthreads();
  int off = 0;
  for (int ww = 0; ww < w; ++ww) off += wq[ww];
  int total = wq[0] + wq[1] + wq[2] + wq[3];
  int pos = off + incl - c0;
#pragma unroll
  for (int u = 0; u < 16; ++u)
    if (a[base + u] != 0.f) idxs[pos++] = (unsigned short)(base + u);
  __syncthreads();

  int c = t * 4;
  float acc0 = 0.f, acc1 = 0.f, acc2 = 0.f, acc3 = 0.f;
  float tt0 = 0.f, tt1 = 0.f, tt2 = 0.f, tt3 = 0.f;
  int nb = ob_step(N_TOK);
  for (int q = 0; q < total; ++q) {
    int j = idxs[q];
    while (j >= nb) {
      tt0 += acc0; tt1 += acc1; tt2 += acc2; tt3 += acc3;
      acc0 = acc1 = acc2 = acc3 = 0.f;
      nb += ob_step(N_TOK - nb);
    }
    float av = a[j];
    float4 xv = *(const float4*)&X[(size_t)j * D_INF + c];
    acc0 = __builtin_fmaf(av, xv.x, acc0);
    acc1 = __builtin_fmaf(av, xv.y, acc1);
    acc2 = __builtin_fmaf(av, xv.z, acc2);
    acc3 = __builtin_fmaf(av, xv.w, acc3);
  }
  tt0 += acc0; tt1 += acc1; tt2 += acc2; tt3 += acc3;
  float4 o = {tt0, tt1, tt2, tt3};
  *(float4*)&C[(size_t)row * D_INF + c] = o;
}

// ---------------- bf16 MFMA GEMM for VALUE-path (fp32 in/out) -----------------
template <int BETA>
__global__ __launch_bounds__(256) void gemm_bf16(const float* __restrict__ A,
                                                 const float* __restrict__ B,
                                                 float* __restrict__ C,
                                                 int M, int N, int K) {
  __shared__ unsigned short As[128 * 32];  // [m][k]
  __shared__ unsigned short Bs[128 * 32];  // [n][k]
  const int t = threadIdx.x;
  const int l = t & 63, w = t >> 6, wr = w >> 1, wc = w & 1;
  const int m0 = blockIdx.y * 128, n0 = blockIdx.x * 128;

  f32x4 acc[4][4];
#pragma unroll
  for (int i = 0; i < 4; ++i)
#pragma unroll
    for (int j = 0; j < 4; ++j)
#pragma unroll
      for (int r = 0; r < 4; ++r) acc[i][j][r] = 0.f;

  const int argp = t >> 3;
  const int acc4 = (t & 7) * 4;
  const int bkb = t >> 5;
  const int bnb = t & 31;

  for (int k0 = 0; k0 < K; k0 += 32) {
#pragma unroll
    for (int u = 0; u < 4; ++u) {
      int row = argp * 4 + u;
      float4 v = *(const float4*)&A[(size_t)(m0 + row) * K + k0 + acc4];
      ushort4 h;
      h.x = f2bf(v.x); h.y = f2bf(v.y); h.z = f2bf(v.z); h.w = f2bf(v.w);
      int idx = (row * 32 + acc4) ^ (((row >> 1) & 3) << 3);
      *(ushort4*)&As[idx] = h;
    }
    {
      float4 r0 = *(const float4*)&B[(size_t)(k0 + bkb * 4 + 0) * N + n0 + bnb * 4];
      float4 r1 = *(const float4*)&B[(size_t)(k0 + bkb * 4 + 1) * N + n0 + bnb * 4];
      float4 r2 = *(const float4*)&B[(size_t)(k0 + bkb * 4 + 2) * N + n0 + bnb * 4];
      float4 r3 = *(const float4*)&B[(size_t)(k0 + bkb * 4 + 3) * N + n0 + bnb * 4];
      float c0[4] = {r0.x, r0.y, r0.z, r0.w};
      float c1[4] = {r1.x, r1.y, r1.z, r1.w};
      float c2[4] = {r2.x, r2.y, r2.z, r2.w};
      float c3[4] = {r3.x, r3.y, r3.z, r3.w};
#pragma unroll
      for (int u = 0; u < 4; ++u) {
        int nrow = bnb * 4 + u;
        ushort4 h;
        h.x = f2bf(c0[u]); h.y = f2bf(c1[u]); h.z = f2bf(c2[u]); h.w = f2bf(c3[u]);
        int idx = (nrow * 32 + bkb * 4) ^ (((nrow >> 1) & 3) << 3);
        *(ushort4*)&Bs[idx] = h;
      }
    }
    __syncthreads();
    bf16x8 af[4], bfv[4];
    const int kseg = (l >> 4) * 8;
#pragma unroll
    for (int fr = 0; fr < 4; ++fr) {
      int row = wr * 64 + fr * 16 + (l & 15);
      int idx = (row * 32 + kseg) ^ (((row >> 1) & 3) << 3);
      af[fr] = *(const bf16x8*)&As[idx];
    }
#pragma unroll
    for (int fc = 0; fc < 4; ++fc) {
      int nrow = wc * 64 + fc * 16 + (l & 15);
      int idx = (nrow * 32 + kseg) ^ (((nrow >> 1) & 3) << 3);
      bfv[fc] = *(const bf16x8*)&Bs[idx];
    }
#pragma unroll
    for (int fr = 0; fr < 4; ++fr)
#pragma unroll
      for (int fc = 0; fc < 4; ++fc)
        acc[fr][fc] = __builtin_amdgcn_mfma_f32_16x16x32_bf16(af[fr], bfv[fc],
                                                              acc[fr][fc], 0, 0, 0);
    __syncthreads();
  }
#pragma unroll
  for (int fr = 0; fr < 4; ++fr) {
#pragma unroll
    for (int fc = 0; fc < 4; ++fc) {
      int rbase = m0 + wr * 64 + fr * 16 + ((l >> 4) << 2);
      int col = n0 + wc * 64 + fc * 16 + (l & 15);
#pragma unroll
      for (int r = 0; r < 4; ++r) {
        size_t off = (size_t)(rbase + r) * N + col;
        float v = acc[fr][fc][r];
        C[off] = BETA ? (C[off] + v) : v;
      }
    }
  }
}

// ---------------- logits = QW @ K^T  (K = QK[:,64:128], ld 128), K=64 ---------
__global__ __launch_bounds__(256) void logits_abt(const float* __restrict__ QW,
                                                  const float* __restrict__ QK,
                                                  float* __restrict__ L) {
  __shared__ float Aq[64][68];
  __shared__ float Bk[64][68];
  int t = threadIdx.x;
  int tx = t & 15, ty = t >> 4;
  int row0 = blockIdx.y * 64, col0 = blockIdx.x * 64;
#pragma unroll
  for (int v = 0; v < 16; ++v) {
    int idx = t + v * 256;
    int c = idx & 63, r = idx >> 6;
    Aq[c][r] = QW[(size_t)(row0 + r) * 64 + c];
    Bk[c][r] = QK[(size_t)(col0 + r) * 128 + 64 + c];
  }
  __syncthreads();
  float acc[4][4] = {};
#pragma unroll
  for (int c0 = 0; c0 < 64; ++c0) {
    float4 a = *(const float4*)&Aq[c0][ty * 4];
    float4 b = *(const float4*)&Bk[c0][tx * 4];
    float av[4] = {a.x, a.y, a.z, a.w};
    float bv[4] = {b.x, b.y, b.z, b.w};
#pragma unroll
    for (int i = 0; i < 4; ++i)
#pragma unroll
      for (int j = 0; j < 4; ++j)
        acc[i][j] = __builtin_fmaf(av[i], bv[j], acc[i][j]);
  }
#pragma unroll
  for (int i = 0; i < 4; ++i) {
    float4 o = {acc[i][0], acc[i][1], acc[i][2], acc[i][3]};
    *(float4*)&L[(size_t)(row0 + ty * 4 + i) * N_TOK + col0 + tx * 4] = o;
  }
}

// ---------------- exact top-p, bitwise-numpy fp32 semantics -------------------
// Sort: STABLE 4-pass LSD radix, 8-bit digits, wave-major layout
// (idx = w*512 + it*64 + lane), per-(digit,wave) histogram + block exclusive
// scan + deterministic leader-cursor ranking (no atomics). Stability holds by
// construction: ranks follow (digit, wave, it, lane) = digit-then-index order.
// Downstream float arithmetic is bit-identical to the R10 passing version.
__global__ __launch_bounds__(512) void topp_exact(float* __restrict__ L) {
  __shared__ unsigned key[N_TOK];   // 16 KB (sorted keys; later raw-value bits)
  __shared__ unsigned scr[N_TOK];   // 16 KB (radix ping-pong; later p[]/sbuf[])
  __shared__ int hist[256 * 8];     // 8 KB  (digit-major, wave-minor)
  __shared__ int wred[8];
  __shared__ float fshare;
  __shared__ float mxs;
  __shared__ int kshare;
  __shared__ int ired[8];

  float* l = L + (size_t)blockIdx.x * N_TOK;
  int t = threadIdx.x;
  int lane = t & 63, w = t >> 6;

  // 1) build descending-monotone u32 keys
  for (int i = t; i < N_TOK; i += 512) key[i] = desc_key(l[i]);
  __syncthreads();

  // 2) stable LSD radix: 4 passes x 8-bit
  unsigned* cur = key;
  unsigned* dst = scr;
  for (int pass = 0; pass < 4; ++pass) {
    int s = pass * 8;
    for (int i = t; i < 2048; i += 512) hist[i] = 0;
    __syncthreads();
    // count: per-wave digit groups, leader does plain RMW on own wave column
    for (int it = 0; it < 8; ++it) {
      unsigned k = cur[w * 512 + it * 64 + lane];
      int d = (k >> s) & 255;
      u64 m = ~0ull;
#pragma unroll
      for (int b = 0; b < 8; ++b) {
        u64 bal = __ballot((d >> b) & 1);
        m &= ((d >> b) & 1) ? bal : ~bal;
      }
      int leader = __ffsll(m) - 1;
      if (lane == leader) hist[d * 8 + w] += (int)__popcll(m);
    }
    __syncthreads();
    // block exclusive scan over hist[0..2047] (linear: digit-major, wave-minor)
    {
      int i0 = t * 4;
      int a0 = hist[i0], a1 = hist[i0 + 1], a2 = hist[i0 + 2], a3 = hist[i0 + 3];
      int sum = a0 + a1 + a2 + a3;
      int incl = sum;
#pragma unroll
      for (int d = 1; d < 64; d <<= 1) {
        int up = __shfl_up(incl, d);
        if (lane >= d) incl += up;
      }
      if (lane == 63) wred[w] = incl;
      __syncthreads();
      int woff = 0;
      for (int ww = 0; ww < w; ++ww) woff += wred[ww];
      int base = woff + incl - sum;
      hist[i0] = base;
      hist[i0 + 1] = base + a0;
      hist[i0 + 2] = base + a0 + a1;
      hist[i0 + 3] = base + a0 + a1 + a2;
    }
    __syncthreads();
    // scatter: leader-cursor ranking (deterministic, stable)
    for (int it = 0; it < 8; ++it) {
      unsigned k = cur[w * 512 + it * 64 + lane];
      int d = (k >> s) & 255;
      u64 m = ~0ull;
#pragma unroll
      for (int b = 0; b < 8; ++b) {
        u64 bal = __ballot((d >> b) & 1);
        m &= ((d >> b) & 1) ? bal : ~bal;
      }
      int leader = __ffsll(m) - 1;
      int old = 0;
      if (lane == leader) {
        old = hist[d * 8 + w];
        hist[d * 8 + w] = old + (int)__popcll(m);
      }
      old = __shfl(old, leader);
      int rank = old + (int)__popcll(m & ((1ull << lane) - 1ull));
      dst[rank] = k;
    }
    __syncthreads();
    unsigned* tmp = cur; cur = dst; dst = tmp;
  }
  // 4 passes (even) -> sorted ascending keys (= values descending) in key[]

  float* p = (float*)scr;  // scr dead; reuse as p[]

  // 3) max + e by rank
  if (t == 0) mxs = desc_key_inv(key[0]);
  __syncthreads();
  float mx = mxs;
  for (int i = t; i < N_TOK; i += 512) p[i] = np_expf(desc_key_inv(key[i]) - mx);
  float tot = npPairwiseSum4096(p, &fshare);  // syncs internally

  // 4) probs = e / tot
  for (int i = t; i < N_TOK; i += 512) p[i] = p[i] / tot;
  __syncthreads();

  // 5) sequential fp32 cumsum with early exit (monotone: once >=0.9f, stays)
  if (t == 0) {
    float c = 0.f;
    int cnt2 = 0;
    for (int j = 0; j < N_TOK; ++j) {
      c += p[j];
      if (c < 0.9f) ++cnt2; else break;
    }
    kshare = (cnt2 + 1 < N_TOK) ? cnt2 + 1 : N_TOK;
  }
  __syncthreads();
  int kcut = kshare;

  // 6) threshold key + tie bookkeeping
  unsigned kt = key[kcut - 1];
  int cg = 0, ce = 0;
  for (int i = t; i < N_TOK; i += 512) {
    unsigned kv = key[i];
    cg += (kv < kt) ? 1 : 0;
    ce += (kv == kt) ? 1 : 0;
  }
  cg = blockSumI512(cg, ired);
  ce = blockSumI512(ce, ired);
  int m_keep = kcut - cg;
  bool allties = (m_keep == ce);
  __syncthreads();

  float* sbuf = (float*)scr;  // p dead after cumsum; reuse for kept-e scatter

  // 7) kept-e scatter (stage raw value bits into key[] for rare partial ties)
  for (int i = t; i < N_TOK; i += 512) {
    float v = l[i];
    unsigned vk = desc_key(v);
    key[i] = __float_as_uint(v);
    bool keep = allties ? (vk <= kt) : (vk < kt);
    sbuf[i] = keep ? np_expf(v - mx) : 0.f;
  }
  __syncthreads();
  if (!allties && t == 0) {
    int taken = 0;
    for (int i = 0; i < N_TOK && taken < m_keep; ++i) {
      float v = __uint_as_float(key[i]);
      if (desc_key(v) == kt) { sbuf[i] = np_expf(v - mx); ++taken; }
    }
  }
  float denom = npPairwiseSum4096(sbuf, &fshare);  // syncs internally

  // 8) A row = sbuf / denom
  for (int i = t; i < N_TOK; i += 512) l[i] = sbuf[i] / denom;
}

// ---------------- Xf = (T + Xf) * rs[row], vectorized float4 ------------------
__global__ __launch_bounds__(256) void xf_update(float* __restrict__ Xf,
                                                 const float* __restrict__ T,
                                                 const float* __restrict__ rs) {
  int idx = blockIdx.x * 256 + threadIdx.x;
  int row = idx >> 8;
  float r = rs[row];
  float4 a = ((const float4*)T)[idx];
  float4 b = ((const float4*)Xf)[idx];
  float4 o;
  o.x = (a.x + b.x) * r; o.y = (a.y + b.y) * r;
  o.z = (a.z + b.z) * r; o.w = (a.w + b.w) * r;
  ((float4*)Xf)[idx] = o;
}

// ---------------- out = LayerNorm(X + Z) * gamma + beta  (Z lives in out) -----
__global__ __launch_bounds__(256) void ln_kernel(const float* __restrict__ X,
                                                 float* __restrict__ out,
                                                 const float* __restrict__ gamma,
                                                 const float* __restrict__ beta) {
  __shared__ float red[4];
  size_t base = (size_t)blockIdx.x * D_INF;
  int t = threadIdx.x;
  float y[4];
  float s = 0.f, ss = 0.f;
#pragma unroll
  for (int i = 0; i < 4; ++i) {
    int c = i * 256 + t;
    y[i] = X[base + c] + out[base + c];
    s += y[i];
    ss += y[i] * y[i];
  }
  s = blockSum(s, red);
  ss = blockSum(ss, red);
  float mean = s * (1.f / 1024.f);
  float var = ss * (1.f / 1024.f) - mean * mean;
  float rstd = rsqrtf(var + 1e-5f);
#pragma unroll
  for (int i = 0; i < 4; ++i) {
    int c = i * 256 + t;
    out[base + c] = (y[i] - mean) * rstd * gamma[c] + beta[c];
  }
}

// -----------------------------------------------------------------------------
extern "C" void kernel_launch(void* const* d_in, const int* in_sizes, int n_in,
                              void* d_out, int out_size, void* d_ws, size_t ws_size,
                              hipStream_t stream) {
  const float* X    = (const float*)d_in[0];
  const float* S    = (const float*)d_in[1];
  const float* W1   = (const float*)d_in[2];
  const float* W2   = (const float*)d_in[3];
  const float* W3   = (const float*)d_in[4];
  const float* U1_0 = (const float*)d_in[5];
  const float* U1_1 = (const float*)d_in[6];
  const float* U2_0 = (const float*)d_in[7];
  const float* U2_1 = (const float*)d_in[8];
  const float* gamma = (const float*)d_in[9];
  const float* beta  = (const float*)d_in[10];
  float* Z = (float*)d_out;

  const size_t ND = (size_t)N_TOK * D_INF;   // 4M
  const size_t NN = (size_t)N_TOK * N_TOK;   // 16M
  float* Xf  = (float*)d_ws;
  float* Xa0 = Xf  + ND;
  float* Xa1 = Xa0 + ND;
  float* T   = Xa1 + ND;
  float* L   = T   + ND;                      // 16M
  float* QKb = L   + NN;
  float* QWb = QKb + (size_t)N_TOK * 128;
  float* Wc  = QWb + (size_t)N_TOK * 64;
  float* rs  = Wc  + (size_t)D_INF * 128;

  hipMemcpyAsync(Xf, X, ND * sizeof(float), hipMemcpyDeviceToDevice, stream);
  rowsum_kernel<<<N_TOK, 256, 0, stream>>>(S, rs);
  wcat_kernel<<<D_INF, 128, 0, stream>>>(W1, W3, Wc);

  dim3 g128(D_INF / 128, N_TOK / 128);

  // ===== step 0 (Xa = X) =====
  gemm_tile<0><<<dim3(2, 64), 256, 0, stream>>>(X, Wc, QKb, N_TOK, 128, D_INF);
  qw_kernel<<<N_TOK / 4, 256, 0, stream>>>(QKb, W2, QWb);
  logits_abt<<<dim3(64, 64), 256, 0, stream>>>(QWb, QKb, L);
  topp_exact<<<N_TOK, 512, 0, stream>>>(L);                       // A1 in L
  gemm_bf16<0><<<g128, 256, 0, stream>>>(S, Xf, T, N_TOK, D_INF, N_TOK);
  xf_update<<<4096, 256, 0, stream>>>(Xf, T, rs);
  // Xa0 = A1 @ X — EXACT, exploiting top-p sparsity (bitwise-identical)
  spmm_exact<<<N_TOK, 256, 0, stream>>>(L, X, Xa0);
  gemm_bf16<0><<<g128, 256, 0, stream>>>(Xf, U1_0, Z, N_TOK, D_INF, D_INF);
  gemm_bf16<1><<<g128, 256, 0, stream>>>(Xa0, U2_0, Z, N_TOK, D_INF, D_INF);

  // ===== step 1 (Xa = Xa0) =====
  gemm_tile<0><<<dim3(2, 64), 256, 0, stream>>>(Xa0, Wc, QKb, N_TOK, 128, D_INF);
  qw_kernel<<<N_TOK / 4, 256, 0, stream>>>(QKb, W2, QWb);
  logits_abt<<<dim3(64, 64), 256, 0, stream>>>(QWb, QKb, L);
  topp_exact<<<N_TOK, 512, 0, stream>>>(L);                       // A2 in L
  gemm_bf16<0><<<g128, 256, 0, stream>>>(S, Xf, T, N_TOK, D_INF, N_TOK);
  xf_update<<<4096, 256, 0, stream>>>(Xf, T, rs);
  gemm_bf16<0><<<g128, 256, 0, stream>>>(L, Xa0, Xa1, N_TOK, D_INF, N_TOK);
  gemm_bf16<1><<<g128, 256, 0, stream>>>(Xf, U1_1, Z, N_TOK, D_INF, D_INF);
  gemm_bf16<1><<<g128, 256, 0, stream>>>(Xa1, U2_1, Z, N_TOK, D_INF, D_INF);

  ln_kernel<<<N_TOK, 256, 0, stream>>>(X, Z, gamma, beta);
}

// Round 13
// 1938.590 us; speedup vs baseline: 3.0887x; 1.0960x over previous
//
#include <hip/hip_runtime.h>
#include <cstddef>
#include <cmath>

#define N_TOK 4096
#define D_INF 1024
#define OB_Q 384  // OpenBLAS SGEMM_DEFAULT_Q for Haswell/ZEN (pypi-wheel on EPYC)

typedef unsigned long long u64;
typedef __attribute__((ext_vector_type(8))) short bf16x8;
typedef __attribute__((ext_vector_type(4))) float f32x4;

// ---------------- block reduction helpers -------------------------------------
__device__ __forceinline__ float blockSum(float x, float* red) {
#pragma unroll
  for (int o = 32; o; o >>= 1) x += __shfl_xor(x, o);
  __syncthreads();
  if ((threadIdx.x & 63) == 0) red[threadIdx.x >> 6] = x;
  __syncthreads();
  return (red[0] + red[1]) + (red[2] + red[3]);
}

__device__ __forceinline__ int blockSumI512(int x, int* red) {
#pragma unroll
  for (int o = 32; o; o >>= 1) x += __shfl_xor(x, o);
  __syncthreads();
  if ((threadIdx.x & 63) == 0) red[threadIdx.x >> 6] = x;
  __syncthreads();
  int s = 0;
#pragma unroll
  for (int w = 0; w < 8; ++w) s += red[w];
  return s;
}

// ---------------- numpy float32 exp, bitwise emulation ------------------------
__device__ __forceinline__ float np_expf(float x) {
  const float log2e = 1.44269504088896341f;  // 0x3FB8AA3B
  float q = __builtin_rintf(x * log2e);
  float r = __builtin_fmaf(q, -0.693359375f, x);        // Cody-Waite hi
  r = __builtin_fmaf(q, 2.12194440e-4f, r);             // Cody-Waite lo (-C2)
  float poly = 1.9875691500e-4f;
  poly = __builtin_fmaf(poly, r, 1.3981999507e-3f);
  poly = __builtin_fmaf(poly, r, 8.3334519073e-3f);
  poly = __builtin_fmaf(poly, r, 4.1665795894e-2f);
  poly = __builtin_fmaf(poly, r, 1.6666665459e-1f);
  poly = __builtin_fmaf(poly, r, 5.0000001201e-1f);
  float zz = r * r;                                     // rounded separately
  poly = __builtin_fmaf(poly, zz, r);
  poly = poly + 1.0f;
  return __builtin_ldexpf(poly, (int)q);                // exact 2^q scale
}

// Rotation mapping for 4096-float LDS buffers: leaf l (128 floats) rotated by l
// -> pairwise leaf reads are bank-conflict-free; contiguous access stays <=2-way.
__device__ __forceinline__ int PIDX(int i) {
  return (i & ~127) | ((i + (i >> 7)) & 127);
}

// ---------------- numpy pairwise_sum over 4096 floats (rotated layout) --------
// 128-elem leaves, 8 accumulators, ((r0+r1)+(r2+r3))+((r4+r5)+(r6+r7)); leaf
// results combined by balanced butterfly (same association as numpy).
__device__ float npPairwiseSum4096Rot(const float* __restrict__ buf, float* share) {
  int t = threadIdx.x;
  __syncthreads();  // buf fully written
  if (t < 32) {
    const float* a = buf + (t << 7);
    float r0 = a[t & 127], r1 = a[(t + 1) & 127], r2 = a[(t + 2) & 127],
          r3 = a[(t + 3) & 127];
    float r4 = a[(t + 4) & 127], r5 = a[(t + 5) & 127], r6 = a[(t + 6) & 127],
          r7 = a[(t + 7) & 127];
    for (int i = 8; i < 128; i += 8) {
      r0 += a[(i + 0 + t) & 127]; r1 += a[(i + 1 + t) & 127];
      r2 += a[(i + 2 + t) & 127]; r3 += a[(i + 3 + t) & 127];
      r4 += a[(i + 4 + t) & 127]; r5 += a[(i + 5 + t) & 127];
      r6 += a[(i + 6 + t) & 127]; r7 += a[(i + 7 + t) & 127];
    }
    float leaf = ((r0 + r1) + (r2 + r3)) + ((r4 + r5) + (r6 + r7));
    leaf += __shfl_xor(leaf, 1);
    leaf += __shfl_xor(leaf, 2);
    leaf += __shfl_xor(leaf, 4);
    leaf += __shfl_xor(leaf, 8);
    leaf += __shfl_xor(leaf, 16);
    if (t == 0) share[0] = leaf;
  }
  __syncthreads();
  return share[0];
}

// key transform: u32 monotone key, ascending key order == descending float order
__device__ __forceinline__ unsigned desc_key(float v) {
  unsigned u = __float_as_uint(v);
  unsigned m = (u & 0x80000000u) ? ~u : (u | 0x80000000u);
  return ~m;
}
__device__ __forceinline__ float desc_key_inv(unsigned k) {
  unsigned m = ~k;
  return __uint_as_float((m & 0x80000000u) ? (m ^ 0x80000000u) : ~m);
}

__device__ __forceinline__ u64 ballot_match8(int d) {
  u64 m = ~0ull;
#pragma unroll
  for (int b = 0; b < 8; ++b) {
    u64 bal = __ballot((d >> b) & 1);
    m &= ((d >> b) & 1) ? bal : ~bal;
  }
  return m;
}

// fp32 -> bf16 round-to-nearest-even (bit trick)
__device__ __forceinline__ unsigned short f2bf(float f) {
  unsigned u = __float_as_uint(f);
  return (unsigned short)((u + 0x7FFFu + ((u >> 16) & 1u)) >> 16);
}

// ---------------- rowsum of S (+1 for identity), store reciprocal -------------
__global__ __launch_bounds__(256) void rowsum_kernel(const float* __restrict__ S,
                                                     float* __restrict__ rs) {
  __shared__ float red[4];
  const float* s = S + (size_t)blockIdx.x * N_TOK;
  float acc = 0.f;
  for (int j = threadIdx.x; j < N_TOK; j += 256) acc += s[j];
  acc = blockSum(acc, red);
  if (threadIdx.x == 0) rs[blockIdx.x] = 1.0f / fmaxf(acc + 1.0f, 1e-12f);
}

// ---------------- Wcat = [W1 | W3]  (1024 x 128) ------------------------------
__global__ void wcat_kernel(const float* __restrict__ W1,
                            const float* __restrict__ W3, float* __restrict__ Wc) {
  int r = blockIdx.x;
  int c = threadIdx.x;
  Wc[r * 128 + c] = (c < 64) ? W1[r * 64 + c] : W3[r * 64 + (c - 64)];
}

// ---------------- QW = Q @ W2 (Q = QK[:,0:64], ld 128) ------------------------
__global__ __launch_bounds__(256) void qw_kernel(const float* __restrict__ QK,
                                                 const float* __restrict__ W2,
                                                 float* __restrict__ QW) {
  __shared__ float w[64][65];
  int t = threadIdx.x;
#pragma unroll
  for (int v = 0; v < 16; ++v) {
    int idx = t + v * 256;
    w[idx >> 6][idx & 63] = W2[idx];
  }
  __syncthreads();
  int row = blockIdx.x * 4 + (t >> 6);
  int c = t & 63;
  const float* q = QK + (size_t)row * 128;
  float acc = 0.f;
#pragma unroll
  for (int k = 0; k < 64; ++k) acc = __builtin_fmaf(q[k], w[k][c], acc);
  QW[(size_t)row * 64 + c] = acc;
}

// ---------------- OpenBLAS kc-chunk step (level3.c balanced tail) -------------
__device__ __forceinline__ int ob_step(int rem) {
  if (rem >= 2 * OB_Q) return OB_Q;
  if (rem > OB_Q) return ((rem / 2) + 15) & ~15;
  return rem;
}

// ---------------- EXACT fp32 tiled GEMM (OpenBLAS-bitwise) --------------------
template <int BETA>
__global__ __launch_bounds__(256) void gemm_tile(const float* __restrict__ A,
                                                 const float* __restrict__ B,
                                                 float* __restrict__ C,
                                                 int M, int N, int K) {
  __shared__ float As[16][68];  // [k][m]
  __shared__ float Bs[16][68];  // [k][n]
  int t = threadIdx.x;
  int tx = t & 15, ty = t >> 4;
  int row0 = blockIdx.y * 64, col0 = blockIdx.x * 64;
  float tot[4][4] = {};
  float acc[4][4] = {};
  int next_b = ob_step(K);
  for (int k0 = 0; k0 < K; k0 += 16) {
    if (k0 == next_b) {
#pragma unroll
      for (int i = 0; i < 4; ++i)
#pragma unroll
        for (int j = 0; j < 4; ++j) { tot[i][j] += acc[i][j]; acc[i][j] = 0.f; }
      next_b = k0 + ob_step(K - k0);
    }
#pragma unroll
    for (int v = 0; v < 4; ++v) {
      int idx = t + v * 256;
      int r = idx >> 4, c = idx & 15;
      As[c][r] = A[(size_t)(row0 + r) * K + k0 + c];
    }
#pragma unroll
    for (int v = 0; v < 4; ++v) {
      int idx = t + v * 256;
      int r = idx >> 6, c = idx & 63;
      Bs[r][c] = B[(size_t)(k0 + r) * N + col0 + c];
    }
    __syncthreads();
#pragma unroll
    for (int kk = 0; kk < 16; ++kk) {
      float4 a = *(const float4*)&As[kk][ty * 4];
      float4 b = *(const float4*)&Bs[kk][tx * 4];
      float av[4] = {a.x, a.y, a.z, a.w};
      float bv[4] = {b.x, b.y, b.z, b.w};
#pragma unroll
      for (int i = 0; i < 4; ++i)
#pragma unroll
        for (int j = 0; j < 4; ++j)
          acc[i][j] = __builtin_fmaf(av[i], bv[j], acc[i][j]);
    }
    __syncthreads();
  }
#pragma unroll
  for (int i = 0; i < 4; ++i)
#pragma unroll
    for (int j = 0; j < 4; ++j) tot[i][j] += acc[i][j];
#pragma unroll
  for (int i = 0; i < 4; ++i) {
    float* cp = &C[(size_t)(row0 + ty * 4 + i) * N + col0 + tx * 4];
    float4 o;
    if (BETA) {
      float4 old = *(const float4*)cp;
      o.x = old.x + tot[i][0]; o.y = old.y + tot[i][1];
      o.z = old.z + tot[i][2]; o.w = old.w + tot[i][3];
    } else {
      o.x = tot[i][0]; o.y = tot[i][1]; o.z = tot[i][2]; o.w = tot[i][3];
    }
    *(float4*)cp = o;
  }
}

// ---------------- EXACT sparse x dense: C = A @ X, A = top-p rows -------------
__global__ __launch_bounds__(256) void spmm_exact(const float* __restrict__ A,
                                                  const float* __restrict__ X,
                                                  float* __restrict__ C) {
  __shared__ unsigned short idxs[N_TOK];  // 8 KB
  __shared__ int wq[4];
  int t = threadIdx.x;
  int lane = t & 63, w = t >> 6;
  int row = blockIdx.x;
  const float* a = A + (size_t)row * N_TOK;

  int base = t * 16;
  int c0 = 0;
#pragma unroll
  for (int u = 0; u < 16; ++u) c0 += (a[base + u] != 0.f) ? 1 : 0;
  int incl = c0;
#pragma unroll
  for (int d = 1; d < 64; d <<= 1) {
    int up = __shfl_up(incl, d);
    if (lane >= d) incl += up;
  }
  if (lane == 63) wq[w] = incl;
  __syncthreads();
  int off = 0;
  for (int ww = 0; ww < w; ++ww) off += wq[ww];
  int total = wq[0] + wq[1] + wq[2] + wq[3];
  int pos = off + incl - c0;
#pragma unroll
  for (int u = 0; u < 16; ++u)
    if (a[base + u] != 0.f) idxs[pos++] = (unsigned short)(base + u);
  __syncthreads();

  int c = t * 4;
  float acc0 = 0.f, acc1 = 0.f, acc2 = 0.f, acc3 = 0.f;
  float tt0 = 0.f, tt1 = 0.f, tt2 = 0.f, tt3 = 0.f;
  int nb = ob_step(N_TOK);
  for (int q = 0; q < total; ++q) {
    int j = idxs[q];
    while (j >= nb) {
      tt0 += acc0; tt1 += acc1; tt2 += acc2; tt3 += acc3;
      acc0 = acc1 = acc2 = acc3 = 0.f;
      nb += ob_step(N_TOK - nb);
    }
    float av = a[j];
    float4 xv = *(const float4*)&X[(size_t)j * D_INF + c];
    acc0 = __builtin_fmaf(av, xv.x, acc0);
    acc1 = __builtin_fmaf(av, xv.y, acc1);
    acc2 = __builtin_fmaf(av, xv.z, acc2);
    acc3 = __builtin_fmaf(av, xv.w, acc3);
  }
  tt0 += acc0; tt1 += acc1; tt2 += acc2; tt3 += acc3;
  float4 o = {tt0, tt1, tt2, tt3};
  *(float4*)&C[(size_t)row * D_INF + c] = o;
}

// ---------------- bf16 MFMA GEMM for VALUE-path (fp32 in/out) -----------------
template <int BETA>
__global__ __launch_bounds__(256) void gemm_bf16(const float* __restrict__ A,
                                                 const float* __restrict__ B,
                                                 float* __restrict__ C,
                                                 int M, int N, int K) {
  __shared__ unsigned short As[128 * 32];  // [m][k]
  __shared__ unsigned short Bs[128 * 32];  // [n][k]
  const int t = threadIdx.x;
  const int l = t & 63, w = t >> 6, wr = w >> 1, wc = w & 1;
  const int m0 = blockIdx.y * 128, n0 = blockIdx.x * 128;

  f32x4 acc[4][4];
#pragma unroll
  for (int i = 0; i < 4; ++i)
#pragma unroll
    for (int j = 0; j < 4; ++j)
#pragma unroll
      for (int r = 0; r < 4; ++r) acc[i][j][r] = 0.f;

  const int argp = t >> 3;
  const int acc4 = (t & 7) * 4;
  const int bkb = t >> 5;
  const int bnb = t & 31;

  for (int k0 = 0; k0 < K; k0 += 32) {
#pragma unroll
    for (int u = 0; u < 4; ++u) {
      int row = argp * 4 + u;
      float4 v = *(const float4*)&A[(size_t)(m0 + row) * K + k0 + acc4];
      ushort4 h;
      h.x = f2bf(v.x); h.y = f2bf(v.y); h.z = f2bf(v.z); h.w = f2bf(v.w);
      int idx = (row * 32 + acc4) ^ (((row >> 1) & 3) << 3);
      *(ushort4*)&As[idx] = h;
    }
    {
      float4 r0 = *(const float4*)&B[(size_t)(k0 + bkb * 4 + 0) * N + n0 + bnb * 4];
      float4 r1 = *(const float4*)&B[(size_t)(k0 + bkb * 4 + 1) * N + n0 + bnb * 4];
      float4 r2 = *(const float4*)&B[(size_t)(k0 + bkb * 4 + 2) * N + n0 + bnb * 4];
      float4 r3 = *(const float4*)&B[(size_t)(k0 + bkb * 4 + 3) * N + n0 + bnb * 4];
      float c0[4] = {r0.x, r0.y, r0.z, r0.w};
      float c1[4] = {r1.x, r1.y, r1.z, r1.w};
      float c2[4] = {r2.x, r2.y, r2.z, r2.w};
      float c3[4] = {r3.x, r3.y, r3.z, r3.w};
#pragma unroll
      for (int u = 0; u < 4; ++u) {
        int nrow = bnb * 4 + u;
        ushort4 h;
        h.x = f2bf(c0[u]); h.y = f2bf(c1[u]); h.z = f2bf(c2[u]); h.w = f2bf(c3[u]);
        int idx = (nrow * 32 + bkb * 4) ^ (((nrow >> 1) & 3) << 3);
        *(ushort4*)&Bs[idx] = h;
      }
    }
    __syncthreads();
    bf16x8 af[4], bfv[4];
    const int kseg = (l >> 4) * 8;
#pragma unroll
    for (int fr = 0; fr < 4; ++fr) {
      int row = wr * 64 + fr * 16 + (l & 15);
      int idx = (row * 32 + kseg) ^ (((row >> 1) & 3) << 3);
      af[fr] = *(const bf16x8*)&As[idx];
    }
#pragma unroll
    for (int fc = 0; fc < 4; ++fc) {
      int nrow = wc * 64 + fc * 16 + (l & 15);
      int idx = (nrow * 32 + kseg) ^ (((nrow >> 1) & 3) << 3);
      bfv[fc] = *(const bf16x8*)&Bs[idx];
    }
#pragma unroll
    for (int fr = 0; fr < 4; ++fr)
#pragma unroll
      for (int fc = 0; fc < 4; ++fc)
        acc[fr][fc] = __builtin_amdgcn_mfma_f32_16x16x32_bf16(af[fr], bfv[fc],
                                                              acc[fr][fc], 0, 0, 0);
    __syncthreads();
  }
#pragma unroll
  for (int fr = 0; fr < 4; ++fr) {
#pragma unroll
    for (int fc = 0; fc < 4; ++fc) {
      int rbase = m0 + wr * 64 + fr * 16 + ((l >> 4) << 2);
      int col = n0 + wc * 64 + fc * 16 + (l & 15);
#pragma unroll
      for (int r = 0; r < 4; ++r) {
        size_t off = (size_t)(rbase + r) * N + col;
        float v = acc[fr][fc][r];
        C[off] = BETA ? (C[off] + v) : v;
      }
    }
  }
}

// ---------------- logits = QW @ K^T  (K = QK[:,64:128], ld 128), K=64 ---------
__global__ __launch_bounds__(256) void logits_abt(const float* __restrict__ QW,
                                                  const float* __restrict__ QK,
                                                  float* __restrict__ L) {
  __shared__ float Aq[64][68];
  __shared__ float Bk[64][68];
  int t = threadIdx.x;
  int tx = t & 15, ty = t >> 4;
  int row0 = blockIdx.y * 64, col0 = blockIdx.x * 64;
#pragma unroll
  for (int v = 0; v < 16; ++v) {
    int idx = t + v * 256;
    int c = idx & 63, r = idx >> 6;
    Aq[c][r] = QW[(size_t)(row0 + r) * 64 + c];
    Bk[c][r] = QK[(size_t)(col0 + r) * 128 + 64 + c];
  }
  __syncthreads();
  float acc[4][4] = {};
#pragma unroll
  for (int c0 = 0; c0 < 64; ++c0) {
    float4 a = *(const float4*)&Aq[c0][ty * 4];
    float4 b = *(const float4*)&Bk[c0][tx * 4];
    float av[4] = {a.x, a.y, a.z, a.w};
    float bv[4] = {b.x, b.y, b.z, b.w};
#pragma unroll
    for (int i = 0; i < 4; ++i)
#pragma unroll
      for (int j = 0; j < 4; ++j)
        acc[i][j] = __builtin_fmaf(av[i], bv[j], acc[i][j]);
  }
#pragma unroll
  for (int i = 0; i < 4; ++i) {
    float4 o = {acc[i][0], acc[i][1], acc[i][2], acc[i][3]};
    *(float4*)&L[(size_t)(row0 + ty * 4 + i) * N_TOK + col0 + tx * 4] = o;
  }
}

// ---------------- exact top-p, bitwise-numpy fp32 semantics -------------------
// STABLE 4-pass LSD radix, fused match: count loop computes per-element
// (within-column offset, digit) via leader-cursor and stores key+pack in regs;
// scatter is ballot-free. hist is u16 wave-major [w][d] (bank = d%32).
// p/sbuf use per-leaf rotation (PIDX) -> conflict-free pairwise leaves.
// All observable float arithmetic bit-identical to the R12 passing version.
__global__ __launch_bounds__(512, 6) void topp_exact(float* __restrict__ L) {
  __shared__ unsigned key[N_TOK];          // 16 KB (sorted keys; later raw bits)
  __shared__ unsigned scr[N_TOK];          // 16 KB (ping-pong; later p[]/sbuf[])
  __shared__ unsigned short hist[8 * 256]; // 4 KB (wave-major columns)
  __shared__ int wred[8];
  __shared__ float fshare;
  __shared__ float mxs;
  __shared__ int kshare;
  __shared__ int ired[8];

  float* l = L + (size_t)blockIdx.x * N_TOK;
  int t = threadIdx.x;
  int lane = t & 63, w = t >> 6;
  u64 below = (lane == 63) ? 0x7FFFFFFFFFFFFFFFull : ((1ull << lane) - 1ull);

  // 1) build descending-monotone u32 keys
  for (int i = t; i < N_TOK; i += 512) key[i] = desc_key(l[i]);
  __syncthreads();

  // 2) stable LSD radix: 4 passes x 8-bit, fused match
  unsigned* cur = key;
  unsigned* dst = scr;
  for (int pass = 0; pass < 4; ++pass) {
    int s = pass * 8;
    for (int i = t; i < 1024; i += 512) ((int*)hist)[i] = 0;
    __syncthreads();
    unsigned myk[8], mypk[8];
    // count + per-element offset capture (leader cursor on own wave column)
#pragma unroll
    for (int it = 0; it < 8; ++it) {
      unsigned k = cur[w * 512 + it * 64 + lane];
      int d = (k >> s) & 255;
      u64 m = ballot_match8(d);
      int leader = __ffsll(m) - 1;
      int before = (int)__popcll(m & below);
      int old = 0;
      if (lane == leader) {
        old = (int)hist[w * 256 + d];
        hist[w * 256 + d] = (unsigned short)(old + (int)__popcll(m));
      }
      old = __shfl(old, leader);
      myk[it] = k;
      mypk[it] = ((unsigned)(old + before) << 8) | (unsigned)d;
    }
    __syncthreads();
    // block exclusive scan over 2048 logical entries (d-major, w-minor)
    {
      int li = t * 4;
      int v0 = hist[((li + 0) & 7) * 256 + ((li + 0) >> 3)];
      int v1 = hist[((li + 1) & 7) * 256 + ((li + 1) >> 3)];
      int v2 = hist[((li + 2) & 7) * 256 + ((li + 2) >> 3)];
      int v3 = hist[((li + 3) & 7) * 256 + ((li + 3) >> 3)];
      int sum = v0 + v1 + v2 + v3;
      int incl = sum;
#pragma unroll
      for (int d = 1; d < 64; d <<= 1) {
        int up = __shfl_up(incl, d);
        if (lane >= d) incl += up;
      }
      if (lane == 63) wred[w] = incl;
      __syncthreads();
      int woff = 0;
      for (int ww = 0; ww < w; ++ww) woff += wred[ww];
      int base = woff + incl - sum;
      hist[((li + 0) & 7) * 256 + ((li + 0) >> 3)] = (unsigned short)base;
      hist[((li + 1) & 7) * 256 + ((li + 1) >> 3)] = (unsigned short)(base + v0);
      hist[((li + 2) & 7) * 256 + ((li + 2) >> 3)] = (unsigned short)(base + v0 + v1);
      hist[((li + 3) & 7) * 256 + ((li + 3) >> 3)] =
          (unsigned short)(base + v0 + v1 + v2);
    }
    __syncthreads();
    // scatter: ballot-free
#pragma unroll
    for (int it = 0; it < 8; ++it) {
      int d = mypk[it] & 255;
      int rank = (int)hist[w * 256 + d] + (int)(mypk[it] >> 8);
      dst[rank] = myk[it];
    }
    __syncthreads();
    unsigned* tmp = cur; cur = dst; dst = tmp;
  }
  // 4 passes (even) -> sorted ascending keys (= values descending) in key[]

  float* p = (float*)scr;  // scr dead; reuse as p[] (rotated layout via PIDX)

  // 3) max + e by rank
  if (t == 0) mxs = desc_key_inv(key[0]);
  __syncthreads();
  float mx = mxs;
  for (int i = t; i < N_TOK; i += 512)
    p[PIDX(i)] = np_expf(desc_key_inv(key[i]) - mx);
  float tot = npPairwiseSum4096Rot(p, &fshare);  // syncs internally

  // 4) probs = e / tot
  for (int i = t; i < N_TOK; i += 512) p[PIDX(i)] = p[PIDX(i)] / tot;
  __syncthreads();

  // 5) sequential fp32 cumsum with early exit (monotone: once >=0.9f, stays)
  if (t == 0) {
    float c = 0.f;
    int cnt2 = 0;
    for (int j = 0; j < N_TOK; ++j) {
      c += p[PIDX(j)];
      if (c < 0.9f) ++cnt2; else break;
    }
    kshare = (cnt2 + 1 < N_TOK) ? cnt2 + 1 : N_TOK;
  }
  __syncthreads();
  int kcut = kshare;

  // 6) threshold key + tie bookkeeping
  unsigned kt = key[kcut - 1];
  int cg = 0, ce = 0;
  for (int i = t; i < N_TOK; i += 512) {
    unsigned kv = key[i];
    cg += (kv < kt) ? 1 : 0;
    ce += (kv == kt) ? 1 : 0;
  }
  cg = blockSumI512(cg, ired);
  ce = blockSumI512(ce, ired);
  int m_keep = kcut - cg;
  bool allties = (m_keep == ce);
  __syncthreads();

  float* sbuf = (float*)scr;  // rotated layout via PIDX

  // 7) kept-e scatter (stage raw value bits into key[] for rare partial ties)
  for (int i = t; i < N_TOK; i += 512) {
    float v = l[i];
    unsigned vk = desc_key(v);
    key[i] = __float_as_uint(v);
    bool keep = allties ? (vk <= kt) : (vk < kt);
    sbuf[PIDX(i)] = keep ? np_expf(v - mx) : 0.f;
  }
  __syncthreads();
  if (!allties && t == 0) {
    int taken = 0;
    for (int i = 0; i < N_TOK && taken < m_keep; ++i) {
      float v = __uint_as_float(key[i]);
      if (desc_key(v) == kt) { sbuf[PIDX(i)] = np_expf(v - mx); ++taken; }
    }
  }
  float denom = npPairwiseSum4096Rot(sbuf, &fshare);  // syncs internally

  // 8) A row = sbuf / denom
  for (int i = t; i < N_TOK; i += 512) l[i] = sbuf[PIDX(i)] / denom;
}

// ---------------- Xf = (T + Xf) * rs[row], vectorized float4 ------------------
__global__ __launch_bounds__(256) void xf_update(float* __restrict__ Xf,
                                                 const float* __restrict__ T,
                                                 const float* __restrict__ rs) {
  int idx = blockIdx.x * 256 + threadIdx.x;
  int row = idx >> 8;
  float r = rs[row];
  float4 a = ((const float4*)T)[idx];
  float4 b = ((const float4*)Xf)[idx];
  float4 o;
  o.x = (a.x + b.x) * r; o.y = (a.y + b.y) * r;
  o.z = (a.z + b.z) * r; o.w = (a.w + b.w) * r;
  ((float4*)Xf)[idx] = o;
}

// ---------------- out = LayerNorm(X + Z) * gamma + beta  (Z lives in out) -----
__global__ __launch_bounds__(256) void ln_kernel(const float* __restrict__ X,
                                                 float* __restrict__ out,
                                                 const float* __restrict__ gamma,
                                                 const float* __restrict__ beta) {
  __shared__ float red[4];
  size_t base = (size_t)blockIdx.x * D_INF;
  int t = threadIdx.x;
  float y[4];
  float s = 0.f, ss = 0.f;
#pragma unroll
  for (int i = 0; i < 4; ++i) {
    int c = i * 256 + t;
    y[i] = X[base + c] + out[base + c];
    s += y[i];
    ss += y[i] * y[i];
  }
  s = blockSum(s, red);
  ss = blockSum(ss, red);
  float mean = s * (1.f / 1024.f);
  float var = ss * (1.f / 1024.f) - mean * mean;
  float rstd = rsqrtf(var + 1e-5f);
#pragma unroll
  for (int i = 0; i < 4; ++i) {
    int c = i * 256 + t;
    out[base + c] = (y[i] - mean) * rstd * gamma[c] + beta[c];
  }
}

// -----------------------------------------------------------------------------
extern "C" void kernel_launch(void* const* d_in, const int* in_sizes, int n_in,
                              void* d_out, int out_size, void* d_ws, size_t ws_size,
                              hipStream_t stream) {
  const float* X    = (const float*)d_in[0];
  const float* S    = (const float*)d_in[1];
  const float* W1   = (const float*)d_in[2];
  const float* W2   = (const float*)d_in[3];
  const float* W3   = (const float*)d_in[4];
  const float* U1_0 = (const float*)d_in[5];
  const float* U1_1 = (const float*)d_in[6];
  const float* U2_0 = (const float*)d_in[7];
  const float* U2_1 = (const float*)d_in[8];
  const float* gamma = (const float*)d_in[9];
  const float* beta  = (const float*)d_in[10];
  float* Z = (float*)d_out;

  const size_t ND = (size_t)N_TOK * D_INF;   // 4M
  const size_t NN = (size_t)N_TOK * N_TOK;   // 16M
  float* Xf  = (float*)d_ws;
  float* Xa0 = Xf  + ND;
  float* Xa1 = Xa0 + ND;
  float* T   = Xa1 + ND;
  float* L   = T   + ND;                      // 16M
  float* QKb = L   + NN;
  float* QWb = QKb + (size_t)N_TOK * 128;
  float* Wc  = QWb + (size_t)N_TOK * 64;
  float* rs  = Wc  + (size_t)D_INF * 128;

  hipMemcpyAsync(Xf, X, ND * sizeof(float), hipMemcpyDeviceToDevice, stream);
  rowsum_kernel<<<N_TOK, 256, 0, stream>>>(S, rs);
  wcat_kernel<<<D_INF, 128, 0, stream>>>(W1, W3, Wc);

  dim3 g128(D_INF / 128, N_TOK / 128);

  // ===== step 0 (Xa = X) =====
  gemm_tile<0><<<dim3(2, 64), 256, 0, stream>>>(X, Wc, QKb, N_TOK, 128, D_INF);
  qw_kernel<<<N_TOK / 4, 256, 0, stream>>>(QKb, W2, QWb);
  logits_abt<<<dim3(64, 64), 256, 0, stream>>>(QWb, QKb, L);
  topp_exact<<<N_TOK, 512, 0, stream>>>(L);                       // A1 in L
  gemm_bf16<0><<<g128, 256, 0, stream>>>(S, Xf, T, N_TOK, D_INF, N_TOK);
  xf_update<<<4096, 256, 0, stream>>>(Xf, T, rs);
  // Xa0 = A1 @ X — EXACT, exploiting top-p sparsity (bitwise-identical)
  spmm_exact<<<N_TOK, 256, 0, stream>>>(L, X, Xa0);
  gemm_bf16<0><<<g128, 256, 0, stream>>>(Xf, U1_0, Z, N_TOK, D_INF, D_INF);
  gemm_bf16<1><<<g128, 256, 0, stream>>>(Xa0, U2_0, Z, N_TOK, D_INF, D_INF);

  // ===== step 1 (Xa = Xa0) =====
  gemm_tile<0><<<dim3(2, 64), 256, 0, stream>>>(Xa0, Wc, QKb, N_TOK, 128, D_INF);
  qw_kernel<<<N_TOK / 4, 256, 0, stream>>>(QKb, W2, QWb);
  logits_abt<<<dim3(64, 64), 256, 0, stream>>>(QWb, QKb, L);
  topp_exact<<<N_TOK, 512, 0, stream>>>(L);                       // A2 in L
  gemm_bf16<0><<<g128, 256, 0, stream>>>(S, Xf, T, N_TOK, D_INF, N_TOK);
  xf_update<<<4096, 256, 0, stream>>>(Xf, T, rs);
  gemm_bf16<0><<<g128, 256, 0, stream>>>(L, Xa0, Xa1, N_TOK, D_INF, N_TOK);
  gemm_bf16<1><<<g128, 256, 0, stream>>>(Xf, U1_1, Z, N_TOK, D_INF, D_INF);
  gemm_bf16<1><<<g128, 256, 0, stream>>>(Xa1, U2_1, Z, N_TOK, D_INF, D_INF);

  ln_kernel<<<N_TOK, 256, 0, stream>>>(X, Z, gamma, beta);
}